// Round 2
// baseline (2374.698 us; speedup 1.0000x reference)
//
#include <hip/hip_runtime.h>
#include <cmath>

namespace {
constexpr int Bz  = 8;
constexpr int L0c = 384;
constexpr int Lc  = 385;
constexpr int Dc  = 128;
constexpr int Hc  = 8;
constexpr int KHc = 16;           // 2 distance groups * 8 heads
constexpr int NITER = 4;
constexpr int BLDc = Bz * Lc * Dc;   // 394240
constexpr float NEGV = 1e9f;

// workspace layout (float offsets)
constexpr size_t OFF_UNARY = 0;
constexpr size_t OFF_QZ    = OFF_UNARY + BLDc;
constexpr size_t OFF_QZS   = OFF_QZ + BLDc;
constexpr size_t OFF_MPAD  = OFF_QZS + BLDc;                 // B*L = 3080 (pad 3584)
constexpr size_t OFF_TAB   = OFF_MPAD + 3584;
constexpr size_t OFF_TBA   = OFF_TAB + (size_t)2 * Hc * Dc * Dc;
constexpr size_t OFF_QI    = OFF_TBA + (size_t)2 * Hc * Dc * Dc;
constexpr size_t SZQ       = (size_t)Bz * KHc * Lc * Dc;     // 6307840
constexpr size_t SZQP      = SZQ + 4096;                     // +31-row overrun pad
constexpr size_t OFF_QJ    = OFF_QI + SZQP;
constexpr size_t OFF_QH    = OFF_QJ + SZQP;
constexpr size_t OFF_GP    = OFF_QH + (size_t)Bz * Hc * Lc * Lc;
constexpr size_t OFF_HP    = OFF_GP + (size_t)Hc * BLDc;
} // namespace

__device__ inline void gAtomicAdd(float* p, float v) {
  unsafeAtomicAdd(p, v);   // global_atomic_add_f32; rounding-order noise << tolerance
}

// ---------------------------------------------------------------- init
__global__ __launch_bounds__(256) void k_init(
    const float* __restrict__ x, const float* __restrict__ mask,
    float* __restrict__ unary, float* __restrict__ qz, float* __restrict__ mpad) {
  int idx = blockIdx.x * 256 + threadIdx.x;
  if (idx >= BLDc) return;
  int d  = idx & (Dc - 1);
  int zi = idx >> 7;
  int i  = zi % Lc;
  int z  = zi / Lc;
  float u = 0.f, m = 1.f;
  if (i > 0) {
    u = x[((size_t)z * L0c + (i - 1)) * Dc + d];
    m = (mask[(size_t)z * L0c + (i - 1)] != 0.f) ? 1.f : 0.f;
  }
  unary[idx] = u;
  qz[idx]    = u * m;
  if (d == 0) mpad[zi] = m;
}

// T[k,a,b,c] (c innermost) -> Tab[kc][a][b], Tba[kc][b][a]
__global__ __launch_bounds__(256) void k_packT(
    const float* __restrict__ T, float* __restrict__ Tab, float* __restrict__ Tba) {
  int idx = blockIdx.x * 256 + threadIdx.x;
  if (idx >= 2 * Dc * Dc * Hc) return;
  int c = idx & 7;
  int t = idx >> 3;
  int b = t & 127; t >>= 7;
  int a = t & 127; t >>= 7;
  int k = t;
  float v = T[idx];
  int kc = k * Hc + c;
  Tab[((size_t)kc * Dc + a) * Dc + b] = v;
  Tba[((size_t)kc * Dc + b) * Dc + a] = v;
}

// ---------------------------------------------------------------- zero partials
__global__ __launch_bounds__(256) void k_zero(float* __restrict__ p, int n4) {
  int i = blockIdx.x * 256 + threadIdx.x;
  if (i < n4) reinterpret_cast<float4*>(p)[i] = make_float4(0.f, 0.f, 0.f, 0.f);
}

// ---------------------------------------------------------------- softmax over d (per (z,i) row)
__global__ __launch_bounds__(128) void k_softmax_z(
    const float* __restrict__ qz, const float* __restrict__ mpad, float* __restrict__ qzs) {
  int row = blockIdx.x;     // z*L + i
  int t = threadIdx.x;
  float v = qz[(size_t)row * Dc + t];
  float m = v;
  #pragma unroll
  for (int o = 32; o > 0; o >>= 1) m = fmaxf(m, __shfl_xor(m, o));
  __shared__ float red[2];
  if ((t & 63) == 0) red[t >> 6] = m;
  __syncthreads();
  m = fmaxf(red[0], red[1]);
  __syncthreads();
  float e = __expf(v - m);
  float s = e;
  #pragma unroll
  for (int o = 32; o > 0; o >>= 1) s += __shfl_xor(s, o);
  if ((t & 63) == 0) red[t >> 6] = s;
  __syncthreads();
  s = red[0] + red[1];
  qzs[(size_t)row * Dc + t] = e / s * mpad[row];
}

// ---------------------------------------------------------------- Qi/Qj: qzs @ Tab / qzs @ Tba
// which=0: Qi[z][kc][i][b] = sum_a qzs[z,i,a]*Tab[kc][a][b]
// which=1: Qj[z][kc][j][a] = sum_b qzs[z,j,b]*Tba[kc][b][a]
__global__ __launch_bounds__(256) void k_qiqj(
    const float* __restrict__ qzs, const float* __restrict__ Tab,
    const float* __restrict__ Tba, float* __restrict__ Qi, float* __restrict__ Qj) {
  __shared__ float Ats[32][68];   // K-major transposed qzs tile
  __shared__ float Bt[32][128];
  const int it = blockIdx.x, z = blockIdx.y;
  const int kc = blockIdx.z >> 1, which = blockIdx.z & 1;
  const int i0 = it * 64;
  const int tid = threadIdx.x, tx = tid & 15, ty = tid >> 4;
  float acc[4][8] = {};
  const float* Az = qzs + (size_t)z * Lc * Dc;
  const float* Tb = (which ? Tba : Tab) + (size_t)kc * Dc * Dc;
  for (int k0 = 0; k0 < Dc; k0 += 32) {
    __syncthreads();
    for (int e = tid; e < 2048; e += 256) {
      int cc = e & 31, rr = e >> 5;
      int i = i0 + rr;
      Ats[cc][rr] = (i < Lc) ? Az[(size_t)i * Dc + k0 + cc] : 0.f;
    }
    for (int e = tid; e < 1024; e += 256) {
      int r = e >> 5, c4 = (e & 31) << 2;
      float4 v = *reinterpret_cast<const float4*>(Tb + (size_t)(k0 + r) * Dc + c4);
      *reinterpret_cast<float4*>(&Bt[r][c4]) = v;
    }
    __syncthreads();
    #pragma unroll 4
    for (int kk = 0; kk < 32; kk++) {
      float4 a4 = *reinterpret_cast<const float4*>(&Ats[kk][ty * 4]);
      float av[4] = {a4.x, a4.y, a4.z, a4.w};
      float4 b0 = *reinterpret_cast<const float4*>(&Bt[kk][tx * 8]);
      float4 b1 = *reinterpret_cast<const float4*>(&Bt[kk][tx * 8 + 4]);
      float bv[8] = {b0.x, b0.y, b0.z, b0.w, b1.x, b1.y, b1.z, b1.w};
      #pragma unroll
      for (int r = 0; r < 4; r++)
        #pragma unroll
        for (int q = 0; q < 8; q++)
          acc[r][q] = fmaf(av[r], bv[q], acc[r][q]);
    }
  }
  float* Out = (which ? Qj : Qi) + (size_t)(z * KHc + kc) * Lc * Dc;
  #pragma unroll
  for (int r = 0; r < 4; r++) {
    int i = i0 + ty * 4 + r;
    if (i >= Lc) break;
    float4* pp = reinterpret_cast<float4*>(Out + (size_t)i * Dc + tx * 8);
    pp[0] = make_float4(acc[r][0], acc[r][1], acc[r][2], acc[r][3]);
    pp[1] = make_float4(acc[r][4], acc[r][5], acc[r][6], acc[r][7]);
  }
}

// ---------------------------------------------------------------- F -> qh logits
// qh[z,c,i,j] = 128 * sum_d Qi[z,k(i,j),c,i,d]*qzs[z,j,d]; diag/invalid -> -1e9
__global__ __launch_bounds__(256) void k_F(
    const float* __restrict__ Qi, const float* __restrict__ qzs,
    const float* __restrict__ mpad, float* __restrict__ qh) {
  __shared__ float A0s[32][68];
  __shared__ float A1s[32][68];
  __shared__ float Bts[32][68];
  const int ti = blockIdx.x / 7, tj = blockIdx.x % 7;
  const int z = blockIdx.y, c = blockIdx.z;
  const int i0 = ti * 64, j0 = tj * 64;
  const bool mixed = (ti == tj);
  const int tid = threadIdx.x;
  const int tx = tid & 15, ty = tid >> 4;
  float acc0[4][4] = {};
  float acc1[4][4] = {};
  const float* Qb0 = Qi + (size_t)(z * KHc + c) * Lc * Dc;        // k=0
  const float* Qb1 = Qi + (size_t)(z * KHc + Hc + c) * Lc * Dc;   // k=1
  const float* Bz_ = qzs + (size_t)z * Lc * Dc;
  const float* Qsel = (!mixed && tj < ti) ? Qb1 : Qb0;
  for (int k0 = 0; k0 < Dc; k0 += 32) {
    __syncthreads();
    for (int e = tid; e < 2048; e += 256) {
      int cc = e & 31, rr = e >> 5;
      int i = i0 + rr, j = j0 + rr;
      A0s[cc][rr] = (i < Lc) ? Qsel[(size_t)i * Dc + k0 + cc] : 0.f;
      if (mixed) A1s[cc][rr] = (i < Lc) ? Qb1[(size_t)i * Dc + k0 + cc] : 0.f;
      Bts[cc][rr] = (j < Lc) ? Bz_[(size_t)j * Dc + k0 + cc] : 0.f;
    }
    __syncthreads();
    #pragma unroll 4
    for (int kk = 0; kk < 32; kk++) {
      float4 a04 = *reinterpret_cast<const float4*>(&A0s[kk][ty * 4]);
      float4 b4  = *reinterpret_cast<const float4*>(&Bts[kk][tx * 4]);
      float a0v[4] = {a04.x, a04.y, a04.z, a04.w};
      float bv[4]  = {b4.x, b4.y, b4.z, b4.w};
      if (mixed) {
        float4 a14 = *reinterpret_cast<const float4*>(&A1s[kk][ty * 4]);
        float a1v[4] = {a14.x, a14.y, a14.z, a14.w};
        #pragma unroll
        for (int r = 0; r < 4; r++)
          #pragma unroll
          for (int q = 0; q < 4; q++) acc1[r][q] = fmaf(a1v[r], bv[q], acc1[r][q]);
      }
      #pragma unroll
      for (int r = 0; r < 4; r++)
        #pragma unroll
        for (int q = 0; q < 4; q++) acc0[r][q] = fmaf(a0v[r], bv[q], acc0[r][q]);
    }
  }
  float* qrow = qh + (size_t)(z * Hc + c) * Lc * Lc;
  #pragma unroll
  for (int r = 0; r < 4; r++) {
    int i = i0 + ty * 4 + r;
    if (i >= Lc) break;
    float mi = mpad[z * Lc + i];
    #pragma unroll
    for (int q = 0; q < 4; q++) {
      int j = j0 + tx * 4 + q;
      if (j >= Lc) continue;
      float mj = mpad[z * Lc + j];
      float val;
      if (i == j || mi == 0.f || mj == 0.f) {
        val = -NEGV;
      } else {
        float s = (mixed && i > j) ? acc1[r][q] : acc0[r][q];
        val = s * 128.f;
      }
      qrow[(size_t)i * Lc + j] = val;
    }
  }
}

// ---------------------------------------------------------------- softmax over j; zero root row i=0
__global__ __launch_bounds__(128) void k_softmax_h(float* __restrict__ qh) {
  const int row = blockIdx.x;      // (z*H + c)*L + i
  const int i = row % Lc;
  const int t = threadIdx.x;
  float* p = qh + (size_t)row * Lc;
  if (i == 0) {
    for (int j = t; j < Lc; j += 128) p[j] = 0.f;
    return;
  }
  float v[4];
  float m = -INFINITY;
  #pragma unroll
  for (int q = 0; q < 4; q++) {
    int j = t + q * 128;
    v[q] = (j < Lc) ? p[j] : -INFINITY;
    m = fmaxf(m, v[q]);
  }
  #pragma unroll
  for (int o = 32; o > 0; o >>= 1) m = fmaxf(m, __shfl_xor(m, o));
  __shared__ float red[2];
  if ((t & 63) == 0) red[t >> 6] = m;
  __syncthreads();
  m = fmaxf(red[0], red[1]);
  __syncthreads();
  float s = 0.f;
  #pragma unroll
  for (int q = 0; q < 4; q++) {
    int j = t + q * 128;
    v[q] = (j < Lc) ? __expf(v[q] - m) : 0.f;
    s += v[q];
  }
  #pragma unroll
  for (int o = 32; o > 0; o >>= 1) s += __shfl_xor(s, o);
  if ((t & 63) == 0) red[t >> 6] = s;
  __syncthreads();
  s = red[0] + red[1];
  float inv = 1.f / s;
  #pragma unroll
  for (int q = 0; q < 4; q++) {
    int j = t + q * 128;
    if (j < Lc) p[j] = v[q] * inv;
  }
}

// ---------------------------------------------------------------- fused G + Hm (split-K, atomic accumulate)
// which=0 (G):  Gp[c][z][row][a] += sum_{k in split} qh[row][k] * Qj[p(row,k)][k][a]
// which=1 (Hm): Hp[c][z][row][b] += sum_{k in split} qh[k][row] * Qi[p(k,row)][k][b]
__global__ __launch_bounds__(256) void k_GH(
    const float* __restrict__ qh, const float* __restrict__ Qi,
    const float* __restrict__ Qj, float* __restrict__ Gp, float* __restrict__ Hp) {
  __shared__ float Qts[32][68];   // [k-chunk][row], K-major
  __shared__ float Bt[32][128];
  const int rt = blockIdx.x;
  const int z  = blockIdx.y;
  const int zc = blockIdx.z;
  const int c = zc & 7, which = (zc >> 3) & 1, sp = zc >> 4;
  const int r0 = rt * 64;
  const int tid = threadIdx.x, tx = tid & 15, ty = tid >> 4;
  const int klo = sp ? 192 : 0, khi = sp ? Lc : 192;
  float acc[4][8] = {};
  const float* qb = qh + (size_t)(z * Hc + c) * Lc * Lc;
  const float* Bsrc = which ? Qi : Qj;
  const int rowmax = min(r0 + 63, Lc - 1);

  for (int kc = klo; kc < khi; kc += 32) {
    const int kmax = min(kc + 31, Lc - 1);
    __syncthreads();
    if (which == 0) {
      // rows=i, k=j: transposed store
      for (int e = tid; e < 2048; e += 256) {
        int cc = e & 31, rr = e >> 5;
        int row = r0 + rr, kg = kc + cc;
        Qts[cc][rr] = (row < Lc && kg < Lc) ? qb[(size_t)row * Lc + kg] : 0.f;
      }
    } else {
      // rows=j, k=i: natural store
      for (int e = tid; e < 2048; e += 256) {
        int cc = e & 63, rr = e >> 6;
        int kg = kc + rr, row = r0 + cc;
        Qts[rr][cc] = (row < Lc && kg < Lc) ? qb[(size_t)kg * Lc + row] : 0.f;
      }
    }
    bool hasP0, hasP1;
    if (which == 0) { hasP0 = (r0 < kmax);    hasP1 = (rowmax > kc); }
    else            { hasP0 = (rowmax > kc);  hasP1 = (r0 < kmax);   }
    const bool needMask = hasP0 && hasP1;
    for (int p = 0; p < 2; p++) {
      if (p == 0 && !hasP0) continue;
      if (p == 1 && !hasP1) continue;
      __syncthreads();
      const float* Bb = Bsrc + (size_t)(z * KHc + p * Hc + c) * Lc * Dc + (size_t)kc * Dc;
      for (int e = tid; e < 1024; e += 256) {
        int r = e >> 5, c4 = (e & 31) << 2;
        float4 v = *reinterpret_cast<const float4*>(Bb + (size_t)r * Dc + c4);
        *reinterpret_cast<float4*>(&Bt[r][c4]) = v;
      }
      __syncthreads();
      const bool wantRowLess = (p == 0) != (which == 1);
      #pragma unroll 4
      for (int kk = 0; kk < 32; kk++) {
        float4 a4 = *reinterpret_cast<const float4*>(&Qts[kk][ty * 4]);
        float av[4] = {a4.x, a4.y, a4.z, a4.w};
        if (needMask) {
          int kg = kc + kk;
          #pragma unroll
          for (int r = 0; r < 4; r++) {
            int row = r0 + ty * 4 + r;
            bool keep = wantRowLess ? (row < kg) : (row > kg);
            if (!keep) av[r] = 0.f;
          }
        }
        float4 b0 = *reinterpret_cast<const float4*>(&Bt[kk][tx * 8]);
        float4 b1 = *reinterpret_cast<const float4*>(&Bt[kk][tx * 8 + 4]);
        float bv[8] = {b0.x, b0.y, b0.z, b0.w, b1.x, b1.y, b1.z, b1.w};
        #pragma unroll
        for (int r = 0; r < 4; r++)
          #pragma unroll
          for (int q = 0; q < 8; q++)
            acc[r][q] = fmaf(av[r], bv[q], acc[r][q]);
      }
    }
  }
  float* outp = (which ? Hp : Gp) + ((size_t)c * Bz + z) * Lc * Dc;
  #pragma unroll
  for (int r = 0; r < 4; r++) {
    int row = r0 + ty * 4 + r;
    if (row >= Lc) break;
    float* pb = outp + (size_t)row * Dc + tx * 8;
    #pragma unroll
    for (int q = 0; q < 8; q++) gAtomicAdd(pb + q, acc[r][q]);
  }
}

// ---------------------------------------------------------------- combine: qz = (unary + G + Hm)*m1
__global__ __launch_bounds__(256) void k_combine(
    const float* __restrict__ unary, const float* __restrict__ Gp,
    const float* __restrict__ Hp, const float* __restrict__ mpad,
    float* __restrict__ qz, float* __restrict__ out, int last) {
  int idx = blockIdx.x * 256 + threadIdx.x;
  if (idx >= BLDc) return;
  int d  = idx & (Dc - 1);
  int zi = idx >> 7;
  int i  = zi % Lc;
  int z  = zi / Lc;
  float s = unary[idx];
  #pragma unroll
  for (int c = 0; c < Hc; c++) s += Gp[(size_t)c * BLDc + idx] + Hp[(size_t)c * BLDc + idx];
  s *= mpad[zi];
  if (last) {
    if (i > 0) out[((size_t)z * L0c + (i - 1)) * Dc + d] = s;
  } else {
    qz[idx] = s;
  }
}

// ---------------------------------------------------------------- launch
extern "C" void kernel_launch(void* const* d_in, const int* in_sizes, int n_in,
                              void* d_out, int out_size, void* d_ws, size_t ws_size,
                              hipStream_t stream) {
  const float* x    = (const float*)d_in[0];
  const float* mask = (const float*)d_in[1];
  const float* tern = (const float*)d_in[2];
  float* ws = (float*)d_ws;

  float* unary = ws + OFF_UNARY;
  float* qz    = ws + OFF_QZ;
  float* qzs   = ws + OFF_QZS;
  float* mpad  = ws + OFF_MPAD;
  float* tab   = ws + OFF_TAB;
  float* tba   = ws + OFF_TBA;
  float* qi    = ws + OFF_QI;
  float* qj    = ws + OFF_QJ;
  float* qh    = ws + OFF_QH;
  float* gp    = ws + OFF_GP;
  float* hp    = ws + OFF_HP;

  k_init<<<(BLDc + 255) / 256, 256, 0, stream>>>(x, mask, unary, qz, mpad);
  k_packT<<<(2 * Dc * Dc * Hc) / 256, 256, 0, stream>>>(tern, tab, tba);

  const int n4 = 4 * BLDc;  // 16*BLDc floats / 4 per float4 (Gp+Hp contiguous)
  for (int it = 0; it < NITER; it++) {
    k_softmax_z<<<Bz * Lc, 128, 0, stream>>>(qz, mpad, qzs);
    k_qiqj<<<dim3(7, Bz, 32), 256, 0, stream>>>(qzs, tab, tba, qi, qj);
    k_F<<<dim3(49, Bz, Hc), 256, 0, stream>>>(qi, qzs, mpad, qh);
    k_softmax_h<<<Bz * Hc * Lc, 128, 0, stream>>>(qh);
    k_zero<<<(n4 + 255) / 256, 256, 0, stream>>>(gp, n4);
    k_GH<<<dim3(7, Bz, 32), 256, 0, stream>>>(qh, qi, qj, gp, hp);
    k_combine<<<(BLDc + 255) / 256, 256, 0, stream>>>(
        unary, gp, hp, mpad, qz, (float*)d_out, (it == NITER - 1) ? 1 : 0);
  }
}

// Round 4
// 1381.105 us; speedup vs baseline: 1.7194x; 1.7194x over previous
//
#include <hip/hip_runtime.h>
#include <cmath>

namespace {
constexpr int Bz  = 8;
constexpr int L0c = 384;
constexpr int Lc  = 385;
constexpr int Dc  = 128;
constexpr int Hc  = 8;
constexpr int KHc = 16;           // 2 distance groups * 8 heads
constexpr int NITER = 4;
constexpr int BLDc = Bz * Lc * Dc;   // 394240
constexpr int QHS = 388;             // qh row stride (float4-aligned)
constexpr float NEGV = 1e9f;

// ---- float workspace offsets
constexpr size_t OFF_UNARY = 0;
constexpr size_t OFF_QZ    = OFF_UNARY + BLDc;
constexpr size_t OFF_QZS   = OFF_QZ + BLDc;
constexpr size_t OFF_MPAD  = OFF_QZS + BLDc;                      // 3584
constexpr size_t OFF_TAB   = OFF_MPAD + 3584;
constexpr size_t OFF_TBA   = OFF_TAB + (size_t)2 * Hc * Dc * Dc;
constexpr size_t OFF_QH    = OFF_TBA + (size_t)2 * Hc * Dc * Dc;  // 64*385*388
constexpr size_t OFF_GP2   = OFF_QH + (size_t)Bz * Hc * Lc * QHS; // 8*BLDc
constexpr size_t OFF_HP2   = OFF_GP2 + (size_t)8 * BLDc;          // 8*BLDc
constexpr size_t FLOAT_END = OFF_HP2 + (size_t)8 * BLDc;          // 17,578,752 fl

// ---- ushort offsets from us = (ushort*)(ws + FLOAT_END)
constexpr size_t SZQ   = (size_t)Bz * KHc * Lc * Dc;              // 6307840
constexpr size_t U_QZH = 0;
constexpr size_t U_QZL = U_QZH + BLDc + 8192;
constexpr size_t U_QIH = U_QZL + BLDc + 8192;
constexpr size_t U_QIL = U_QIH + SZQ + 8192;
constexpr size_t U_QJH = U_QIL + SZQ + 8192;
constexpr size_t U_QJL = U_QJH + SZQ + 8192;
// total ws ~= 122.5 MB
} // namespace

typedef __attribute__((ext_vector_type(8))) short bh8_t;
typedef __attribute__((ext_vector_type(4))) float f4_t;
#define MFMA16(a, b, c) __builtin_amdgcn_mfma_f32_16x16x32_bf16((a), (b), (c), 0, 0, 0)

__device__ inline ushort f2bf(float x) {
  uint u = __float_as_uint(x);
  uint r = (u + 0x7FFFu + ((u >> 16) & 1u)) >> 16;
  return (ushort)r;
}
__device__ inline float bf2f(ushort h) { return __uint_as_float(((uint)h) << 16); }
// swizzled ushort offset of 16B group (row, g): bijective, conflict-free b128 reads
__device__ inline int slot8(int row, int g) { return (((row << 2) | (g ^ (row & 3))) << 3); }

union U8 { ushort u[8]; uint4 v; };

// ---------------------------------------------------------------- init
__global__ __launch_bounds__(256) void k_init(
    const float* __restrict__ x, const float* __restrict__ mask,
    float* __restrict__ unary, float* __restrict__ qz, float* __restrict__ mpad) {
  int idx = blockIdx.x * 256 + threadIdx.x;
  if (idx >= BLDc) return;
  int d  = idx & (Dc - 1);
  int zi = idx >> 7;
  int i  = zi % Lc;
  int z  = zi / Lc;
  float u = 0.f, m = 1.f;
  if (i > 0) {
    u = x[((size_t)z * L0c + (i - 1)) * Dc + d];
    m = (mask[(size_t)z * L0c + (i - 1)] != 0.f) ? 1.f : 0.f;
  }
  unary[idx] = u;
  qz[idx]    = u * m;
  if (d == 0) mpad[zi] = m;
}

// T[k,a,b,c] -> Tab[kc][a][b], Tba[kc][b][a]
__global__ __launch_bounds__(256) void k_packT(
    const float* __restrict__ T, float* __restrict__ Tab, float* __restrict__ Tba) {
  int idx = blockIdx.x * 256 + threadIdx.x;
  if (idx >= 2 * Dc * Dc * Hc) return;
  int c = idx & 7;
  int t = idx >> 3;
  int b = t & 127; t >>= 7;
  int a = t & 127; t >>= 7;
  int k = t;
  float v = T[idx];
  int kc = k * Hc + c;
  Tab[((size_t)kc * Dc + a) * Dc + b] = v;
  Tba[((size_t)kc * Dc + b) * Dc + a] = v;
}

// ---------------------------------------------------------------- softmax over d + hi/lo emit
__global__ __launch_bounds__(128) void k_softmax_z(
    const float* __restrict__ qz, const float* __restrict__ mpad,
    float* __restrict__ qzs, ushort* __restrict__ qhi, ushort* __restrict__ qlo) {
  int row = blockIdx.x;     // z*L + i
  int t = threadIdx.x;
  float v = qz[(size_t)row * Dc + t];
  float m = v;
  #pragma unroll
  for (int o = 32; o > 0; o >>= 1) m = fmaxf(m, __shfl_xor(m, o));
  __shared__ float red[2];
  if ((t & 63) == 0) red[t >> 6] = m;
  __syncthreads();
  m = fmaxf(red[0], red[1]);
  __syncthreads();
  float e = __expf(v - m);
  float s = e;
  #pragma unroll
  for (int o = 32; o > 0; o >>= 1) s += __shfl_xor(s, o);
  if ((t & 63) == 0) red[t >> 6] = s;
  __syncthreads();
  s = red[0] + red[1];
  float r = e / s * mpad[row];
  size_t o = (size_t)row * Dc + t;
  qzs[o] = r;
  ushort h = f2bf(r);
  qhi[o] = h;
  qlo[o] = f2bf(r - bf2f(h));
}

// ---------------------------------------------------------------- Qi/Qj (fp32 VALU, hi/lo bf16 out)
// which=0: Qi[z][kc][i][b] = sum_a qzs[z,i,a]*Tab[kc][a][b]
// which=1: Qj[z][kc][j][a] = sum_b qzs[z,j,b]*Tba[kc][b][a]
__global__ __launch_bounds__(256) void k_qiqj(
    const float* __restrict__ qzs, const float* __restrict__ Tab,
    const float* __restrict__ Tba, ushort* __restrict__ QiH, ushort* __restrict__ QiL,
    ushort* __restrict__ QjH, ushort* __restrict__ QjL) {
  __shared__ float Ats[32][68];
  __shared__ float Bt[32][128];
  const int it = blockIdx.x, z = blockIdx.y;
  const int kc = blockIdx.z >> 1, which = blockIdx.z & 1;
  const int i0 = it * 64;
  const int tid = threadIdx.x, tx = tid & 15, ty = tid >> 4;
  float acc[4][8] = {};
  const float* Az = qzs + (size_t)z * Lc * Dc;
  const float* Tb = (which ? Tba : Tab) + (size_t)kc * Dc * Dc;
  for (int k0 = 0; k0 < Dc; k0 += 32) {
    __syncthreads();
    for (int e = tid; e < 2048; e += 256) {
      int cc = e & 31, rr = e >> 5;
      int i = i0 + rr;
      Ats[cc][rr] = (i < Lc) ? Az[(size_t)i * Dc + k0 + cc] : 0.f;
    }
    for (int e = tid; e < 1024; e += 256) {
      int r = e >> 5, c4 = (e & 31) << 2;
      float4 v = *reinterpret_cast<const float4*>(Tb + (size_t)(k0 + r) * Dc + c4);
      *reinterpret_cast<float4*>(&Bt[r][c4]) = v;
    }
    __syncthreads();
    #pragma unroll 4
    for (int kk = 0; kk < 32; kk++) {
      float4 a4 = *reinterpret_cast<const float4*>(&Ats[kk][ty * 4]);
      float av[4] = {a4.x, a4.y, a4.z, a4.w};
      float4 b0 = *reinterpret_cast<const float4*>(&Bt[kk][tx * 8]);
      float4 b1 = *reinterpret_cast<const float4*>(&Bt[kk][tx * 8 + 4]);
      float bv[8] = {b0.x, b0.y, b0.z, b0.w, b1.x, b1.y, b1.z, b1.w};
      #pragma unroll
      for (int r = 0; r < 4; r++)
        #pragma unroll
        for (int q = 0; q < 8; q++)
          acc[r][q] = fmaf(av[r], bv[q], acc[r][q]);
    }
  }
  ushort* OH = which ? QjH : QiH;
  ushort* OL = which ? QjL : QiL;
  const size_t base = (size_t)(z * KHc + kc) * Lc * Dc;
  #pragma unroll
  for (int r = 0; r < 4; r++) {
    int i = i0 + ty * 4 + r;
    if (i >= Lc) break;
    size_t o = base + (size_t)i * Dc + tx * 8;
    U8 h, l;
    #pragma unroll
    for (int q = 0; q < 8; q++) {
      float v = acc[r][q];
      h.u[q] = f2bf(v);
      l.u[q] = f2bf(v - bf2f(h.u[q]));
    }
    *reinterpret_cast<uint4*>(OH + o) = h.v;
    *reinterpret_cast<uint4*>(OL + o) = l.v;
  }
}

// ---------------------------------------------------------------- F -> qh logits (MFMA, split-bf16)
__global__ __launch_bounds__(256) void k_F(
    const ushort* __restrict__ QiH, const ushort* __restrict__ QiL,
    const ushort* __restrict__ qzH, const ushort* __restrict__ qzL,
    const float* __restrict__ mpad, float* __restrict__ qh) {
  __shared__ ushort A0h[2048], A0l[2048], A1h[2048], A1l[2048], Bh[2048], Bl[2048];
  const int ti = blockIdx.x / 7, tj = blockIdx.x % 7;
  const int z = blockIdx.y, c = blockIdx.z;
  const int i0 = ti * 64, j0 = tj * 64;
  const bool mixed = (ti == tj);
  const int tid = threadIdx.x;
  const int wid = tid >> 6, ln = tid & 63;
  const int wr = wid >> 1, wc = wid & 1;
  const int lr = ln & 15, lg = ln >> 4;
  const ushort* p0h = QiH + (size_t)(z * KHc + c) * Lc * Dc;        // k=0
  const ushort* p0l = QiL + (size_t)(z * KHc + c) * Lc * Dc;
  const ushort* p1h = QiH + (size_t)(z * KHc + Hc + c) * Lc * Dc;   // k=1
  const ushort* p1l = QiL + (size_t)(z * KHc + Hc + c) * Lc * Dc;
  const ushort* bhp = qzH + (size_t)z * Lc * Dc;
  const ushort* blp = qzL + (size_t)z * Lc * Dc;
  const ushort* sAh = (!mixed && tj < ti) ? p1h : p0h;
  const ushort* sAl = (!mixed && tj < ti) ? p1l : p0l;
  f4_t acc0[2][2] = {};
  f4_t acc1[2][2] = {};
  const int srow = tid >> 2, sg = tid & 3;
  const int so = slot8(srow, sg);
  const bool aok = (i0 + srow) < Lc;
  const bool bok = (j0 + srow) < Lc;
  const size_t aoff = (size_t)(i0 + srow) * Dc + sg * 8;
  const size_t boff = (size_t)(j0 + srow) * Dc + sg * 8;
  const uint4 zq = make_uint4(0u, 0u, 0u, 0u);
  for (int k0 = 0; k0 < Dc; k0 += 32) {
    __syncthreads();
    *reinterpret_cast<uint4*>(&A0h[so]) = aok ? *reinterpret_cast<const uint4*>(sAh + aoff + k0) : zq;
    *reinterpret_cast<uint4*>(&A0l[so]) = aok ? *reinterpret_cast<const uint4*>(sAl + aoff + k0) : zq;
    *reinterpret_cast<uint4*>(&Bh[so])  = bok ? *reinterpret_cast<const uint4*>(bhp + boff + k0) : zq;
    *reinterpret_cast<uint4*>(&Bl[so])  = bok ? *reinterpret_cast<const uint4*>(blp + boff + k0) : zq;
    if (mixed) {
      *reinterpret_cast<uint4*>(&A1h[so]) = aok ? *reinterpret_cast<const uint4*>(p1h + aoff + k0) : zq;
      *reinterpret_cast<uint4*>(&A1l[so]) = aok ? *reinterpret_cast<const uint4*>(p1l + aoff + k0) : zq;
    }
    __syncthreads();
    bh8_t ah[2], al[2], bhv[2], blv[2];
    #pragma unroll
    for (int f = 0; f < 2; f++) {
      int ra = wr * 32 + f * 16 + lr;
      ah[f] = *reinterpret_cast<const bh8_t*>(&A0h[slot8(ra, lg)]);
      al[f] = *reinterpret_cast<const bh8_t*>(&A0l[slot8(ra, lg)]);
      int rb = wc * 32 + f * 16 + lr;
      bhv[f] = *reinterpret_cast<const bh8_t*>(&Bh[slot8(rb, lg)]);
      blv[f] = *reinterpret_cast<const bh8_t*>(&Bl[slot8(rb, lg)]);
    }
    #pragma unroll
    for (int fi = 0; fi < 2; fi++)
      #pragma unroll
      for (int fj = 0; fj < 2; fj++) {
        acc0[fi][fj] = MFMA16(ah[fi], bhv[fj], acc0[fi][fj]);
        acc0[fi][fj] = MFMA16(ah[fi], blv[fj], acc0[fi][fj]);
        acc0[fi][fj] = MFMA16(al[fi], bhv[fj], acc0[fi][fj]);
      }
    if (mixed) {
      bh8_t a1h[2], a1l[2];
      #pragma unroll
      for (int f = 0; f < 2; f++) {
        int ra = wr * 32 + f * 16 + lr;
        a1h[f] = *reinterpret_cast<const bh8_t*>(&A1h[slot8(ra, lg)]);
        a1l[f] = *reinterpret_cast<const bh8_t*>(&A1l[slot8(ra, lg)]);
      }
      #pragma unroll
      for (int fi = 0; fi < 2; fi++)
        #pragma unroll
        for (int fj = 0; fj < 2; fj++) {
          acc1[fi][fj] = MFMA16(a1h[fi], bhv[fj], acc1[fi][fj]);
          acc1[fi][fj] = MFMA16(a1h[fi], blv[fj], acc1[fi][fj]);
          acc1[fi][fj] = MFMA16(a1l[fi], bhv[fj], acc1[fi][fj]);
        }
    }
  }
  float* qrow = qh + (size_t)(z * Hc + c) * Lc * QHS;
  #pragma unroll
  for (int fi = 0; fi < 2; fi++)
    #pragma unroll
    for (int fj = 0; fj < 2; fj++)
      #pragma unroll
      for (int r = 0; r < 4; r++) {
        int i = i0 + wr * 32 + fi * 16 + lg * 4 + r;
        int j = j0 + wc * 32 + fj * 16 + lr;
        if (i >= Lc || j >= Lc) continue;
        float mi = mpad[z * Lc + i], mj = mpad[z * Lc + j];
        float val;
        if (i == j || mi == 0.f || mj == 0.f) val = -NEGV;
        else {
          float sacc = (mixed && i > j) ? acc1[fi][fj][r] : acc0[fi][fj][r];
          val = sacc * 128.f;
        }
        qrow[(size_t)i * QHS + j] = val;
      }
}

// ---------------------------------------------------------------- softmax over j; zero root row
__global__ __launch_bounds__(128) void k_softmax_h(float* __restrict__ qh) {
  const int row = blockIdx.x;      // (z*H + c)*L + i
  const int i = row % Lc;
  const int t = threadIdx.x;
  float* p = qh + (size_t)row * QHS;
  if (i == 0) {
    for (int j = t; j < Lc; j += 128) p[j] = 0.f;
    return;
  }
  float v[4];
  float m = -INFINITY;
  #pragma unroll
  for (int q = 0; q < 4; q++) {
    int j = t + q * 128;
    v[q] = (j < Lc) ? p[j] : -INFINITY;
    m = fmaxf(m, v[q]);
  }
  #pragma unroll
  for (int o = 32; o > 0; o >>= 1) m = fmaxf(m, __shfl_xor(m, o));
  __shared__ float red[2];
  if ((t & 63) == 0) red[t >> 6] = m;
  __syncthreads();
  m = fmaxf(red[0], red[1]);
  __syncthreads();
  float s = 0.f;
  #pragma unroll
  for (int q = 0; q < 4; q++) {
    int j = t + q * 128;
    v[q] = (j < Lc) ? __expf(v[q] - m) : 0.f;
    s += v[q];
  }
  #pragma unroll
  for (int o = 32; o > 0; o >>= 1) s += __shfl_xor(s, o);
  if ((t & 63) == 0) red[t >> 6] = s;
  __syncthreads();
  s = red[0] + red[1];
  float inv = 1.f / s;
  #pragma unroll
  for (int q = 0; q < 4; q++) {
    int j = t + q * 128;
    if (j < Lc) p[j] = v[q] * inv;
  }
}

// ---------------------------------------------------------------- fused G/Hm (MFMA split-bf16, in-LDS transposes)
// which=0 (G):  out[i][a] = sum_j qh[i][j] * Qj^{k(i,j)}[j][a]
// which=1 (Hm): out[j][b] = sum_i qh[i][j] * Qi^{k(i,j)}[i][b]
__global__ __launch_bounds__(256) void k_GH2(
    const float* __restrict__ qh,
    const ushort* __restrict__ QiH, const ushort* __restrict__ QiL,
    const ushort* __restrict__ QjH, const ushort* __restrict__ QjL,
    float* __restrict__ Gp2, float* __restrict__ Hp2) {
  __shared__ ushort Ath[1024], Atl[1024];
  __shared__ ushort Bth[4096], Btl[4096];
  const int r0 = blockIdx.x * 32;
  const int z  = blockIdx.y;
  const int bz = blockIdx.z;
  const int c = bz & 7, which = bz >> 3;
  const int tid = threadIdx.x;
  const int wid = tid >> 6, ln = tid & 63;
  const int wr = wid >> 1, wc = wid & 1;
  const int lr = ln & 15, lg = ln >> 4;
  const int rowmax = min(r0 + 31, Lc - 1);
  const float* qhp = qh + (size_t)(z * Hc + c) * Lc * QHS;
  const ushort* BH = which ? QiH : QjH;
  const ushort* BL = which ? QiL : QjL;
  f4_t acc[4] = {};
  const uint4 zq = make_uint4(0u, 0u, 0u, 0u);

  for (int kc = 0; kc < Lc; kc += 32) {
    const int kmax = min(kc + 31, Lc - 1);
    for (int p = 0; p < 2; p++) {
      const bool rl = (p == 0) != (which == 1);   // keep R<kg if rl else R>kg
      const bool has = rl ? (r0 < kmax) : (rowmax > kc);
      if (!has) continue;
      __syncthreads();
      // ---- stage A (32 rows x 32 k), masked hi/lo
      if (which == 0) {
        // A[row=i][k=j]: direct rows of qh
        int arow = tid >> 3, c4 = (tid & 7) * 4;
        int R = r0 + arow;
        float4 v = make_float4(0.f, 0.f, 0.f, 0.f);
        if (R < Lc && kc + c4 < Lc)
          v = *reinterpret_cast<const float4*>(qhp + (size_t)R * QHS + kc + c4);
        float vv[4] = {v.x, v.y, v.z, v.w};
        ushort4 h4, l4;
        ushort* hp = reinterpret_cast<ushort*>(&h4);
        ushort* lp = reinterpret_cast<ushort*>(&l4);
        #pragma unroll
        for (int q = 0; q < 4; q++) {
          int kg = kc + c4 + q;
          bool keep = (R < Lc) && (kg < Lc) && (rl ? (R < kg) : (R > kg));
          float x = keep ? vv[q] : 0.f;
          ushort hh = f2bf(x);
          hp[q] = hh;
          lp[q] = f2bf(x - bf2f(hh));
        }
        int off = slot8(arow, c4 >> 3) + (c4 & 4);
        *reinterpret_cast<ushort4*>(&Ath[off]) = h4;
        *reinterpret_cast<ushort4*>(&Atl[off]) = l4;
      } else {
        // A[row=j][k=i]: transpose 32x32 block of qh
        int rr = tid >> 3, c4 = (tid & 7) * 4;    // rr: k-local (i), c4: j-local base
        int I = kc + rr;
        float4 v = make_float4(0.f, 0.f, 0.f, 0.f);
        if (I < Lc && r0 + c4 + 4 <= QHS)
          v = *reinterpret_cast<const float4*>(qhp + (size_t)I * QHS + r0 + c4);
        float vv[4] = {v.x, v.y, v.z, v.w};
        #pragma unroll
        for (int q = 0; q < 4; q++) {
          int R = r0 + c4 + q;   // j
          bool keep = (I < Lc) && (R < Lc) && (rl ? (R < I) : (R > I));
          float x = keep ? vv[q] : 0.f;
          ushort hh = f2bf(x);
          int off = slot8(c4 + q, rr >> 3) + (rr & 7);
          Ath[off] = hh;
          Atl[off] = f2bf(x - bf2f(hh));
        }
      }
      // ---- stage B (128 cols x 32 k): transpose from row-major [k][col]
      {
        const ushort* BpH = BH + (size_t)(z * KHc + p * Hc + c) * Lc * Dc;
        const ushort* BpL = BL + (size_t)(z * KHc + p * Hc + c) * Lc * Dc;
        #pragma unroll
        for (int rep = 0; rep < 2; rep++) {
          int e = tid + rep * 256;       // 0..511
          int krow = e >> 4, cg = e & 15;
          int K = kc + krow;
          uint4 vh = zq, vl = zq;
          if (K < Lc) {
            vh = *reinterpret_cast<const uint4*>(BpH + (size_t)K * Dc + cg * 8);
            vl = *reinterpret_cast<const uint4*>(BpL + (size_t)K * Dc + cg * 8);
          }
          const ushort* uh = reinterpret_cast<const ushort*>(&vh);
          const ushort* ul = reinterpret_cast<const ushort*>(&vl);
          #pragma unroll
          for (int q = 0; q < 8; q++) {
            int col = cg * 8 + q;
            int off = slot8(col, krow >> 3) + (krow & 7);
            Bth[off] = uh[q];
            Btl[off] = ul[q];
          }
        }
      }
      __syncthreads();
      // ---- fragments + 12 MFMA (3-term split)
      int raoff = slot8(wr * 16 + lr, lg);
      bh8_t ah = *reinterpret_cast<const bh8_t*>(&Ath[raoff]);
      bh8_t al = *reinterpret_cast<const bh8_t*>(&Atl[raoff]);
      #pragma unroll
      for (int fj = 0; fj < 4; fj++) {
        int rboff = slot8(wc * 64 + fj * 16 + lr, lg);
        bh8_t bh = *reinterpret_cast<const bh8_t*>(&Bth[rboff]);
        bh8_t bl = *reinterpret_cast<const bh8_t*>(&Btl[rboff]);
        acc[fj] = MFMA16(ah, bh, acc[fj]);
        acc[fj] = MFMA16(ah, bl, acc[fj]);
        acc[fj] = MFMA16(al, bh, acc[fj]);
      }
    }
  }
  float* outp = (which ? Hp2 : Gp2) + ((size_t)c * Bz + z) * (size_t)Lc * Dc;
  #pragma unroll
  for (int r = 0; r < 4; r++) {
    int row = r0 + wr * 16 + lg * 4 + r;
    if (row >= Lc) continue;
    #pragma unroll
    for (int fj = 0; fj < 4; fj++) {
      int col = wc * 64 + fj * 16 + lr;
      outp[(size_t)row * Dc + col] = acc[fj][r];
    }
  }
}

// ---------------------------------------------------------------- combine: qz = (unary + G + Hm)*m1
__global__ __launch_bounds__(256) void k_combine(
    const float* __restrict__ unary, const float* __restrict__ Gp2,
    const float* __restrict__ Hp2, const float* __restrict__ mpad,
    float* __restrict__ qz, float* __restrict__ out, int last) {
  int idx = blockIdx.x * 256 + threadIdx.x;
  if (idx >= BLDc) return;
  int d  = idx & (Dc - 1);
  int zi = idx >> 7;
  int i  = zi % Lc;
  int z  = zi / Lc;
  float s = unary[idx];
  #pragma unroll
  for (int q = 0; q < 8; q++) s += Gp2[(size_t)q * BLDc + idx] + Hp2[(size_t)q * BLDc + idx];
  s *= mpad[zi];
  if (last) {
    if (i > 0) out[((size_t)z * L0c + (i - 1)) * Dc + d] = s;
  } else {
    qz[idx] = s;
  }
}

// ---------------------------------------------------------------- launch
extern "C" void kernel_launch(void* const* d_in, const int* in_sizes, int n_in,
                              void* d_out, int out_size, void* d_ws, size_t ws_size,
                              hipStream_t stream) {
  const float* x    = (const float*)d_in[0];
  const float* mask = (const float*)d_in[1];
  const float* tern = (const float*)d_in[2];
  float* ws = (float*)d_ws;

  float* unary = ws + OFF_UNARY;
  float* qz    = ws + OFF_QZ;
  float* qzs   = ws + OFF_QZS;
  float* mpad  = ws + OFF_MPAD;
  float* tab   = ws + OFF_TAB;
  float* tba   = ws + OFF_TBA;
  float* qh    = ws + OFF_QH;
  float* gp2   = ws + OFF_GP2;
  float* hp2   = ws + OFF_HP2;
  ushort* us   = (ushort*)(ws + FLOAT_END);
  ushort* qzH  = us + U_QZH;
  ushort* qzL  = us + U_QZL;
  ushort* qiH  = us + U_QIH;
  ushort* qiL  = us + U_QIL;
  ushort* qjH  = us + U_QJH;
  ushort* qjL  = us + U_QJL;

  k_init<<<(BLDc + 255) / 256, 256, 0, stream>>>(x, mask, unary, qz, mpad);
  k_packT<<<(2 * Dc * Dc * Hc) / 256, 256, 0, stream>>>(tern, tab, tba);

  for (int it = 0; it < NITER; it++) {
    k_softmax_z<<<Bz * Lc, 128, 0, stream>>>(qz, mpad, qzs, qzH, qzL);
    k_qiqj<<<dim3(7, Bz, 32), 256, 0, stream>>>(qzs, tab, tba, qiH, qiL, qjH, qjL);
    k_F<<<dim3(49, Bz, Hc), 256, 0, stream>>>(qiH, qiL, qzH, qzL, mpad, qh);
    k_softmax_h<<<Bz * Hc * Lc, 128, 0, stream>>>(qh);
    k_GH2<<<dim3(13, Bz, 16), 256, 0, stream>>>(qh, qiH, qiL, qjH, qjL, gp2, hp2);
    k_combine<<<(BLDc + 255) / 256, 256, 0, stream>>>(
        unary, gp2, hp2, mpad, qz, (float*)d_out, (it == NITER - 1) ? 1 : 0);
  }
}

// Round 9
// 1004.476 us; speedup vs baseline: 2.3641x; 1.3750x over previous
//
#include <hip/hip_runtime.h>
#include <cmath>

namespace {
constexpr int Bz  = 8;
constexpr int L0c = 384;
constexpr int Lc  = 385;
constexpr int Dc  = 128;
constexpr int Hc  = 8;
constexpr int KHc = 16;           // 2 distance groups * 8 heads
constexpr int NITER = 4;
constexpr int BLDc = Bz * Lc * Dc;   // 394240
constexpr int QHS = 388;             // qh fp32 row stride (float4-aligned)
constexpr int LpadT = 400;           // transposed-plane row stride (ushort)
constexpr float NEGV = 1e9f;

// ---- float workspace offsets
constexpr size_t OFF_UNARY = 0;
constexpr size_t OFF_QZ    = OFF_UNARY + BLDc;
constexpr size_t OFF_QZS   = OFF_QZ + BLDc;
constexpr size_t OFF_MPAD  = OFF_QZS + BLDc;                      // 3584
constexpr size_t OFF_TAB   = OFF_MPAD + 3584;
constexpr size_t OFF_TBA   = OFF_TAB + (size_t)2 * Hc * Dc * Dc;
constexpr size_t OFF_QH    = OFF_TBA + (size_t)2 * Hc * Dc * Dc;  // 64*385*388
constexpr size_t OFF_GP2   = OFF_QH + (size_t)Bz * Hc * Lc * QHS; // 8*BLDc
constexpr size_t OFF_HP2   = OFF_GP2 + (size_t)8 * BLDc;          // 8*BLDc
constexpr size_t FLOAT_END = OFF_HP2 + (size_t)8 * BLDc;

// ---- ushort offsets from us = (ushort*)(ws + FLOAT_END)
constexpr size_t SZQ    = (size_t)Bz * KHc * Lc * Dc;             // 6307840
constexpr size_t SZQT   = (size_t)Bz * KHc * Dc * LpadT;          // 6553600
constexpr size_t U_QZH  = 0;
constexpr size_t U_QZL  = U_QZH + BLDc + 8192;
constexpr size_t U_QIH  = U_QZL + BLDc + 8192;
constexpr size_t U_QIL  = U_QIH + SZQ + 8192;
constexpr size_t U_QITH = U_QIL + SZQ + 8192;
constexpr size_t U_QITL = U_QITH + SZQT + 64;
constexpr size_t U_QJTH = U_QITL + SZQT + 64;
constexpr size_t U_QJTL = U_QJTH + SZQT + 64;
// total ws ~= 149 MB
} // namespace

typedef __attribute__((ext_vector_type(8))) short bh8_t;
typedef __attribute__((ext_vector_type(4))) float f4_t;
#define MFMA16(a, b, c) __builtin_amdgcn_mfma_f32_16x16x32_bf16((a), (b), (c), 0, 0, 0)

__device__ inline ushort f2bf(float x) {
  uint u = __float_as_uint(x);
  uint r = (u + 0x7FFFu + ((u >> 16) & 1u)) >> 16;
  return (ushort)r;
}
__device__ inline float bf2f(ushort h) { return __uint_as_float(((uint)h) << 16); }
// swizzled ushort offset of 16B group (row, g): bijective, conflict-free b128 access
__device__ inline int slot8(int row, int g) { return (((row << 2) | (g ^ (row & 3))) << 3); }

union U8 { ushort u[8]; uint4 v; };

// ---------------------------------------------------------------- init
__global__ __launch_bounds__(256) void k_init(
    const float* __restrict__ x, const float* __restrict__ mask,
    float* __restrict__ unary, float* __restrict__ qz, float* __restrict__ mpad) {
  int idx = blockIdx.x * 256 + threadIdx.x;
  if (idx >= BLDc) return;
  int d  = idx & (Dc - 1);
  int zi = idx >> 7;
  int i  = zi % Lc;
  int z  = zi / Lc;
  float u = 0.f, m = 1.f;
  if (i > 0) {
    u = x[((size_t)z * L0c + (i - 1)) * Dc + d];
    m = (mask[(size_t)z * L0c + (i - 1)] != 0.f) ? 1.f : 0.f;
  }
  unary[idx] = u;
  qz[idx]    = u * m;
  if (d == 0) mpad[zi] = m;
}

// T[k,a,b,c] -> Tab[kc][a][b], Tba[kc][b][a]
__global__ __launch_bounds__(256) void k_packT(
    const float* __restrict__ T, float* __restrict__ Tab, float* __restrict__ Tba) {
  int idx = blockIdx.x * 256 + threadIdx.x;
  if (idx >= 2 * Dc * Dc * Hc) return;
  int c = idx & 7;
  int t = idx >> 3;
  int b = t & 127; t >>= 7;
  int a = t & 127; t >>= 7;
  int k = t;
  float v = T[idx];
  int kc = k * Hc + c;
  Tab[((size_t)kc * Dc + a) * Dc + b] = v;
  Tba[((size_t)kc * Dc + b) * Dc + a] = v;
}

// ---------------------------------------------------------------- softmax over d + hi/lo emit
__global__ __launch_bounds__(128) void k_softmax_z(
    const float* __restrict__ qz, const float* __restrict__ mpad,
    float* __restrict__ qzs, ushort* __restrict__ qhi, ushort* __restrict__ qlo) {
  int row = blockIdx.x;     // z*L + i
  int t = threadIdx.x;
  float v = qz[(size_t)row * Dc + t];
  float m = v;
  #pragma unroll
  for (int o = 32; o > 0; o >>= 1) m = fmaxf(m, __shfl_xor(m, o));
  __shared__ float red[2];
  if ((t & 63) == 0) red[t >> 6] = m;
  __syncthreads();
  m = fmaxf(red[0], red[1]);
  __syncthreads();
  float e = __expf(v - m);
  float s = e;
  #pragma unroll
  for (int o = 32; o > 0; o >>= 1) s += __shfl_xor(s, o);
  if ((t & 63) == 0) red[t >> 6] = s;
  __syncthreads();
  s = red[0] + red[1];
  float r = e / s * mpad[row];
  size_t o = (size_t)row * Dc + t;
  qzs[o] = r;
  ushort h = f2bf(r);
  qhi[o] = h;
  qlo[o] = f2bf(r - bf2f(h));
}

// ---------------------------------------------------------------- Qi/Qj (fp32 VALU)
// which=0: Qi[z][kc][i][b] = sum_a qzs[z,i,a]*Tab  -> row-major hi/lo (for F) + transposed hi/lo (for Hm)
// which=1: Qj[z][kc][j][a] = sum_b qzs[z,j,b]*Tba  -> transposed hi/lo only (for G)
__global__ __launch_bounds__(256) void k_qiqj(
    const float* __restrict__ qzs, const float* __restrict__ Tab,
    const float* __restrict__ Tba, ushort* __restrict__ QiH, ushort* __restrict__ QiL,
    ushort* __restrict__ QiTH, ushort* __restrict__ QiTL,
    ushort* __restrict__ QjTH, ushort* __restrict__ QjTL) {
  __shared__ __align__(16) char pool[25088];
  float* Ats = (float*)pool;                 // [32][68]
  float* Bt  = (float*)(pool + 8704);        // [32][128]
  const int it = blockIdx.x, z = blockIdx.y;
  const int kc = blockIdx.z >> 1, which = blockIdx.z & 1;
  const int i0 = it * 64;
  const int tid = threadIdx.x, tx = tid & 15, ty = tid >> 4;
  float acc[4][8] = {};
  const float* Az = qzs + (size_t)z * Lc * Dc;
  const float* Tb = (which ? Tba : Tab) + (size_t)kc * Dc * Dc;
  for (int k0 = 0; k0 < Dc; k0 += 32) {
    __syncthreads();
    for (int e = tid; e < 2048; e += 256) {
      int cc = e & 31, rr = e >> 5;
      int i = i0 + rr;
      Ats[cc * 68 + rr] = (i < Lc) ? Az[(size_t)i * Dc + k0 + cc] : 0.f;
    }
    for (int e = tid; e < 1024; e += 256) {
      int r = e >> 5, c4 = (e & 31) << 2;
      float4 v = *reinterpret_cast<const float4*>(Tb + (size_t)(k0 + r) * Dc + c4);
      *reinterpret_cast<float4*>(&Bt[r * 128 + c4]) = v;
    }
    __syncthreads();
    #pragma unroll 4
    for (int kk = 0; kk < 32; kk++) {
      float4 a4 = *reinterpret_cast<const float4*>(&Ats[kk * 68 + ty * 4]);
      float av[4] = {a4.x, a4.y, a4.z, a4.w};
      float4 b0 = *reinterpret_cast<const float4*>(&Bt[kk * 128 + tx * 8]);
      float4 b1 = *reinterpret_cast<const float4*>(&Bt[kk * 128 + tx * 8 + 4]);
      float bv[8] = {b0.x, b0.y, b0.z, b0.w, b1.x, b1.y, b1.z, b1.w};
      #pragma unroll
      for (int r = 0; r < 4; r++)
        #pragma unroll
        for (int q = 0; q < 8; q++)
          acc[r][q] = fmaf(av[r], bv[q], acc[r][q]);
    }
  }
  // hi/lo in registers
  U8 h[4], l[4];
  #pragma unroll
  for (int r = 0; r < 4; r++)
    #pragma unroll
    for (int q = 0; q < 8; q++) {
      float v = acc[r][q];
      h[r].u[q] = f2bf(v);
      l[r].u[q] = f2bf(v - bf2f(h[r].u[q]));
    }
  const size_t plane = (size_t)(z * KHc + kc);
  if (which == 0) {  // row-major for F
    const size_t base = plane * Lc * Dc;
    #pragma unroll
    for (int r = 0; r < 4; r++) {
      int i = i0 + ty * 4 + r;
      if (i >= Lc) break;
      size_t o = base + (size_t)i * Dc + tx * 8;
      *reinterpret_cast<uint4*>(QiH + o) = h[r].v;
      *reinterpret_cast<uint4*>(QiL + o) = l[r].v;
    }
  }
  // transposed emit via LDS (stride 72 so uint4 rows stay 16B-aligned)
  ushort* TH = which ? QjTH : QiTH;
  ushort* TL = which ? QjTL : QiTL;
  ushort* Tr = (ushort*)pool;                // [128][72]
  const size_t tbase = plane * Dc * LpadT;
  for (int pass = 0; pass < 2; pass++) {
    __syncthreads();
    #pragma unroll
    for (int q = 0; q < 8; q++) {
      int a = tx * 8 + q;
      ushort4 w;
      if (pass == 0) w = make_ushort4(h[0].u[q], h[1].u[q], h[2].u[q], h[3].u[q]);
      else           w = make_ushort4(l[0].u[q], l[1].u[q], l[2].u[q], l[3].u[q]);
      *reinterpret_cast<ushort4*>(&Tr[a * 72 + ty * 4]) = w;
    }
    __syncthreads();
    ushort* Out = pass ? TL : TH;
    for (int e = tid; e < 1024; e += 256) {
      int row = e >> 3, g = e & 7;
      int j = i0 + g * 8;
      if (j >= LpadT) continue;
      uint4 v = *reinterpret_cast<const uint4*>(&Tr[row * 72 + g * 8]);
      *reinterpret_cast<uint4*>(Out + tbase + (size_t)row * LpadT + j) = v;
    }
  }
}

// ---------------------------------------------------------------- F -> qh logits (MFMA, split-bf16)
__global__ __launch_bounds__(256) void k_F(
    const ushort* __restrict__ QiH, const ushort* __restrict__ QiL,
    const ushort* __restrict__ qzH, const ushort* __restrict__ qzL,
    const float* __restrict__ mpad, float* __restrict__ qh) {
  __shared__ ushort A0h[2048], A0l[2048], A1h[2048], A1l[2048], Bh[2048], Bl[2048];
  const int ti = blockIdx.x / 7, tj = blockIdx.x % 7;
  const int z = blockIdx.y, c = blockIdx.z;
  const int i0 = ti * 64, j0 = tj * 64;
  const bool mixed = (ti == tj);
  const int tid = threadIdx.x;
  const int wid = tid >> 6, ln = tid & 63;
  const int wr = wid >> 1, wc = wid & 1;
  const int lr = ln & 15, lg = ln >> 4;
  const ushort* p0h = QiH + (size_t)(z * KHc + c) * Lc * Dc;
  const ushort* p0l = QiL + (size_t)(z * KHc + c) * Lc * Dc;
  const ushort* p1h = QiH + (size_t)(z * KHc + Hc + c) * Lc * Dc;
  const ushort* p1l = QiL + (size_t)(z * KHc + Hc + c) * Lc * Dc;
  const ushort* bhp = qzH + (size_t)z * Lc * Dc;
  const ushort* blp = qzL + (size_t)z * Lc * Dc;
  const ushort* sAh = (!mixed && tj < ti) ? p1h : p0h;
  const ushort* sAl = (!mixed && tj < ti) ? p1l : p0l;
  f4_t acc0[2][2] = {};
  f4_t acc1[2][2] = {};
  const int srow = tid >> 2, sg = tid & 3;
  const int so = slot8(srow, sg);
  const bool aok = (i0 + srow) < Lc;
  const bool bok = (j0 + srow) < Lc;
  const size_t aoff = (size_t)(i0 + srow) * Dc + sg * 8;
  const size_t boff = (size_t)(j0 + srow) * Dc + sg * 8;
  const uint4 zq = make_uint4(0u, 0u, 0u, 0u);
  for (int k0 = 0; k0 < Dc; k0 += 32) {
    __syncthreads();
    *reinterpret_cast<uint4*>(&A0h[so]) = aok ? *reinterpret_cast<const uint4*>(sAh + aoff + k0) : zq;
    *reinterpret_cast<uint4*>(&A0l[so]) = aok ? *reinterpret_cast<const uint4*>(sAl + aoff + k0) : zq;
    *reinterpret_cast<uint4*>(&Bh[so])  = bok ? *reinterpret_cast<const uint4*>(bhp + boff + k0) : zq;
    *reinterpret_cast<uint4*>(&Bl[so])  = bok ? *reinterpret_cast<const uint4*>(blp + boff + k0) : zq;
    if (mixed) {
      *reinterpret_cast<uint4*>(&A1h[so]) = aok ? *reinterpret_cast<const uint4*>(p1h + aoff + k0) : zq;
      *reinterpret_cast<uint4*>(&A1l[so]) = aok ? *reinterpret_cast<const uint4*>(p1l + aoff + k0) : zq;
    }
    __syncthreads();
    bh8_t ah[2], al[2], bhv[2], blv[2];
    #pragma unroll
    for (int f = 0; f < 2; f++) {
      int ra = wr * 32 + f * 16 + lr;
      ah[f] = *reinterpret_cast<const bh8_t*>(&A0h[slot8(ra, lg)]);
      al[f] = *reinterpret_cast<const bh8_t*>(&A0l[slot8(ra, lg)]);
      int rb = wc * 32 + f * 16 + lr;
      bhv[f] = *reinterpret_cast<const bh8_t*>(&Bh[slot8(rb, lg)]);
      blv[f] = *reinterpret_cast<const bh8_t*>(&Bl[slot8(rb, lg)]);
    }
    #pragma unroll
    for (int fi = 0; fi < 2; fi++)
      #pragma unroll
      for (int fj = 0; fj < 2; fj++) {
        acc0[fi][fj] = MFMA16(ah[fi], bhv[fj], acc0[fi][fj]);
        acc0[fi][fj] = MFMA16(ah[fi], blv[fj], acc0[fi][fj]);
        acc0[fi][fj] = MFMA16(al[fi], bhv[fj], acc0[fi][fj]);
      }
    if (mixed) {
      bh8_t a1h[2], a1l[2];
      #pragma unroll
      for (int f = 0; f < 2; f++) {
        int ra = wr * 32 + f * 16 + lr;
        a1h[f] = *reinterpret_cast<const bh8_t*>(&A1h[slot8(ra, lg)]);
        a1l[f] = *reinterpret_cast<const bh8_t*>(&A1l[slot8(ra, lg)]);
      }
      #pragma unroll
      for (int fi = 0; fi < 2; fi++)
        #pragma unroll
        for (int fj = 0; fj < 2; fj++) {
          acc1[fi][fj] = MFMA16(a1h[fi], bhv[fj], acc1[fi][fj]);
          acc1[fi][fj] = MFMA16(a1h[fi], blv[fj], acc1[fi][fj]);
          acc1[fi][fj] = MFMA16(a1l[fi], bhv[fj], acc1[fi][fj]);
        }
    }
  }
  float* qrow = qh + (size_t)(z * Hc + c) * Lc * QHS;
  #pragma unroll
  for (int fi = 0; fi < 2; fi++)
    #pragma unroll
    for (int fj = 0; fj < 2; fj++)
      #pragma unroll
      for (int r = 0; r < 4; r++) {
        int i = i0 + wr * 32 + fi * 16 + lg * 4 + r;
        int j = j0 + wc * 32 + fj * 16 + lr;
        if (i >= Lc || j >= Lc) continue;
        float mi = mpad[z * Lc + i], mj = mpad[z * Lc + j];
        float val;
        if (i == j || mi == 0.f || mj == 0.f) val = -NEGV;
        else {
          float sacc = (mixed && i > j) ? acc1[fi][fj][r] : acc0[fi][fj][r];
          val = sacc * 128.f;
        }
        qrow[(size_t)i * QHS + j] = val;
      }
}

// ---------------------------------------------------------------- softmax over j; zero root row
__global__ __launch_bounds__(128) void k_softmax_h(float* __restrict__ qh) {
  const int row = blockIdx.x;      // (z*H + c)*L + i
  const int i = row % Lc;
  const int t = threadIdx.x;
  float* p = qh + (size_t)row * QHS;
  if (i == 0) {
    for (int j = t; j < Lc; j += 128) p[j] = 0.f;
    return;
  }
  float v[4];
  float m = -INFINITY;
  #pragma unroll
  for (int q = 0; q < 4; q++) {
    int j = t + q * 128;
    v[q] = (j < Lc) ? p[j] : -INFINITY;
    m = fmaxf(m, v[q]);
  }
  #pragma unroll
  for (int o = 32; o > 0; o >>= 1) m = fmaxf(m, __shfl_xor(m, o));
  __shared__ float red[2];
  if ((t & 63) == 0) red[t >> 6] = m;
  __syncthreads();
  m = fmaxf(red[0], red[1]);
  __syncthreads();
  float s = 0.f;
  #pragma unroll
  for (int q = 0; q < 4; q++) {
    int j = t + q * 128;
    v[q] = (j < Lc) ? __expf(v[q] - m) : 0.f;
    s += v[q];
  }
  #pragma unroll
  for (int o = 32; o > 0; o >>= 1) s += __shfl_xor(s, o);
  if ((t & 63) == 0) red[t >> 6] = s;
  __syncthreads();
  s = red[0] + red[1];
  float inv = 1.f / s;
  #pragma unroll
  for (int q = 0; q < 4; q++) {
    int j = t + q * 128;
    if (j < Lc) p[j] = v[q] * inv;
  }
}

// ---------------------------------------------------------------- fused G/Hm (MFMA split-bf16, uint4 staging)
// which=0 (G):  out[i][a] = sum_j qh[i][j] * QjT^{k(i,j)}[a][j]
// which=1 (Hm): out[j][b] = sum_i qh[i][j] * QiT^{k(i,j)}[b][i]
__global__ __launch_bounds__(256) void k_GH2(
    const float* __restrict__ qh,
    const ushort* __restrict__ QiTH, const ushort* __restrict__ QiTL,
    const ushort* __restrict__ QjTH, const ushort* __restrict__ QjTL,
    float* __restrict__ Gp2, float* __restrict__ Hp2) {
  __shared__ ushort Ath[2048], Atl[2048];
  __shared__ ushort Bth[4096], Btl[4096];
  const int r0 = blockIdx.x * 64;
  const int z  = blockIdx.y;
  const int bz = blockIdx.z;
  const int c = bz & 7, which = bz >> 3;
  const int tid = threadIdx.x;
  const int wid = tid >> 6, ln = tid & 63;
  const int wr = wid >> 1, wc = wid & 1;
  const int lr = ln & 15, lg = ln >> 4;
  const int rowmax = min(r0 + 63, Lc - 1);
  const float* qhp = qh + (size_t)(z * Hc + c) * Lc * QHS;
  const ushort* BH = which ? QiTH : QjTH;
  const ushort* BL = which ? QiTL : QjTL;
  f4_t acc[2][4] = {};
  const uint4 zq = make_uint4(0u, 0u, 0u, 0u);

  for (int kc = 0; kc < Lc; kc += 32) {
    const int kmax = min(kc + 31, Lc - 1);
    for (int p = 0; p < 2; p++) {
      const bool rl = (p == 0) != (which == 1);   // keep R<kg if rl else R>kg
      const bool has = rl ? (r0 < kmax) : (rowmax > kc);
      if (!has) continue;
      __syncthreads();
      // ---- stage A (64 rows x 32 k), masked hi/lo
      if (which == 0) {
        int srow = tid >> 2, sg = tid & 3;
        int R = r0 + srow;
        float4 v0 = make_float4(0.f,0.f,0.f,0.f), v1 = v0;
        if (R < Lc) {
          v0 = *reinterpret_cast<const float4*>(qhp + (size_t)R * QHS + kc + sg * 8);
          v1 = *reinterpret_cast<const float4*>(qhp + (size_t)R * QHS + kc + sg * 8 + 4);
        }
        float vv[8] = {v0.x, v0.y, v0.z, v0.w, v1.x, v1.y, v1.z, v1.w};
        U8 hh, ll;
        #pragma unroll
        for (int q = 0; q < 8; q++) {
          int kg = kc + sg * 8 + q;
          bool keep = (R < Lc) && (kg < Lc) && (rl ? (R < kg) : (R > kg));
          float x = keep ? vv[q] : 0.f;
          hh.u[q] = f2bf(x);
          ll.u[q] = f2bf(x - bf2f(hh.u[q]));
        }
        int off = slot8(srow, sg);
        *reinterpret_cast<uint4*>(&Ath[off]) = hh.v;
        *reinterpret_cast<uint4*>(&Atl[off]) = ll.v;
      } else {
        // A[row=j][k=i]: transpose 32x64 block of qh
        int rr = tid >> 3, cg = tid & 7;   // rr: i-local, cg: j-group
        int I = kc + rr;
        float4 v0 = make_float4(0.f,0.f,0.f,0.f), v1 = v0;
        if (I < Lc) {
          v0 = *reinterpret_cast<const float4*>(qhp + (size_t)I * QHS + r0 + cg * 8);
          v1 = *reinterpret_cast<const float4*>(qhp + (size_t)I * QHS + r0 + cg * 8 + 4);
        }
        float vv[8] = {v0.x, v0.y, v0.z, v0.w, v1.x, v1.y, v1.z, v1.w};
        #pragma unroll
        for (int q = 0; q < 8; q++) {
          int jl = cg * 8 + q;
          int R = r0 + jl;
          bool keep = (I < Lc) && (R < Lc) && (rl ? (R < I) : (R > I));
          float x = keep ? vv[q] : 0.f;
          ushort hh = f2bf(x);
          int off = slot8(jl, rr >> 3) + (rr & 7);
          Ath[off] = hh;
          Atl[off] = f2bf(x - bf2f(hh));
        }
      }
      // ---- stage B (128 rows x 32 k) from transposed planes: pure uint4
      {
        const size_t pb = (size_t)(z * KHc + p * Hc + c) * Dc * LpadT + kc;
        #pragma unroll
        for (int rep = 0; rep < 2; rep++) {
          int e = tid + rep * 256;       // 0..511
          int brow = e >> 2, g = e & 3;
          size_t go = pb + (size_t)brow * LpadT + g * 8;
          int off = slot8(brow, g);
          *reinterpret_cast<uint4*>(&Bth[off]) = *reinterpret_cast<const uint4*>(BH + go);
          *reinterpret_cast<uint4*>(&Btl[off]) = *reinterpret_cast<const uint4*>(BL + go);
        }
      }
      __syncthreads();
      // ---- fragments + MFMA (3-term split)
      bh8_t ah[2], al[2];
      #pragma unroll
      for (int fi = 0; fi < 2; fi++) {
        int ra = wr * 32 + fi * 16 + lr;
        ah[fi] = *reinterpret_cast<const bh8_t*>(&Ath[slot8(ra, lg)]);
        al[fi] = *reinterpret_cast<const bh8_t*>(&Atl[slot8(ra, lg)]);
      }
      #pragma unroll
      for (int fj = 0; fj < 4; fj++) {
        int rb = wc * 64 + fj * 16 + lr;
        bh8_t bh = *reinterpret_cast<const bh8_t*>(&Bth[slot8(rb, lg)]);
        bh8_t bl = *reinterpret_cast<const bh8_t*>(&Btl[slot8(rb, lg)]);
        #pragma unroll
        for (int fi = 0; fi < 2; fi++) {
          acc[fi][fj] = MFMA16(ah[fi], bh, acc[fi][fj]);
          acc[fi][fj] = MFMA16(ah[fi], bl, acc[fi][fj]);
          acc[fi][fj] = MFMA16(al[fi], bh, acc[fi][fj]);
        }
      }
    }
  }
  float* outp = (which ? Hp2 : Gp2) + ((size_t)c * Bz + z) * (size_t)Lc * Dc;
  #pragma unroll
  for (int fi = 0; fi < 2; fi++)
    #pragma unroll
    for (int r = 0; r < 4; r++) {
      int row = r0 + wr * 32 + fi * 16 + lg * 4 + r;
      if (row >= Lc) continue;
      #pragma unroll
      for (int fj = 0; fj < 4; fj++) {
        int col = wc * 64 + fj * 16 + lr;
        outp[(size_t)row * Dc + col] = acc[fi][fj][r];
      }
    }
}

// ---------------------------------------------------------------- combine: qz = (unary + G + Hm)*m1
__global__ __launch_bounds__(256) void k_combine(
    const float* __restrict__ unary, const float* __restrict__ Gp2,
    const float* __restrict__ Hp2, const float* __restrict__ mpad,
    float* __restrict__ qz, float* __restrict__ out, int last) {
  int idx = blockIdx.x * 256 + threadIdx.x;
  if (idx >= BLDc) return;
  int d  = idx & (Dc - 1);
  int zi = idx >> 7;
  int i  = zi % Lc;
  int z  = zi / Lc;
  float s = unary[idx];
  #pragma unroll
  for (int q = 0; q < 8; q++) s += Gp2[(size_t)q * BLDc + idx] + Hp2[(size_t)q * BLDc + idx];
  s *= mpad[zi];
  if (last) {
    if (i > 0) out[((size_t)z * L0c + (i - 1)) * Dc + d] = s;
  } else {
    qz[idx] = s;
  }
}

// ---------------------------------------------------------------- launch
extern "C" void kernel_launch(void* const* d_in, const int* in_sizes, int n_in,
                              void* d_out, int out_size, void* d_ws, size_t ws_size,
                              hipStream_t stream) {
  const float* x    = (const float*)d_in[0];
  const float* mask = (const float*)d_in[1];
  const float* tern = (const float*)d_in[2];
  float* ws = (float*)d_ws;

  float* unary = ws + OFF_UNARY;
  float* qz    = ws + OFF_QZ;
  float* qzs   = ws + OFF_QZS;
  float* mpad  = ws + OFF_MPAD;
  float* tab   = ws + OFF_TAB;
  float* tba   = ws + OFF_TBA;
  float* qh    = ws + OFF_QH;
  float* gp2   = ws + OFF_GP2;
  float* hp2   = ws + OFF_HP2;
  ushort* us   = (ushort*)(ws + FLOAT_END);
  ushort* qzH  = us + U_QZH;
  ushort* qzL  = us + U_QZL;
  ushort* qiH  = us + U_QIH;
  ushort* qiL  = us + U_QIL;
  ushort* qiTH = us + U_QITH;
  ushort* qiTL = us + U_QITL;
  ushort* qjTH = us + U_QJTH;
  ushort* qjTL = us + U_QJTL;

  k_init<<<(BLDc + 255) / 256, 256, 0, stream>>>(x, mask, unary, qz, mpad);
  k_packT<<<(2 * Dc * Dc * Hc) / 256, 256, 0, stream>>>(tern, tab, tba);

  for (int it = 0; it < NITER; it++) {
    k_softmax_z<<<Bz * Lc, 128, 0, stream>>>(qz, mpad, qzs, qzH, qzL);
    k_qiqj<<<dim3(7, Bz, 32), 256, 0, stream>>>(qzs, tab, tba, qiH, qiL,
                                                qiTH, qiTL, qjTH, qjTL);
    k_F<<<dim3(49, Bz, Hc), 256, 0, stream>>>(qiH, qiL, qzH, qzL, mpad, qh);
    k_softmax_h<<<Bz * Hc * Lc, 128, 0, stream>>>(qh);
    k_GH2<<<dim3(7, Bz, 16), 256, 0, stream>>>(qh, qiTH, qiTL, qjTH, qjTL, gp2, hp2);
    k_combine<<<(BLDc + 255) / 256, 256, 0, stream>>>(
        unary, gp2, hp2, mpad, qz, (float*)d_out, (it == NITER - 1) ? 1 : 0);
  }
}

// Round 12
// 626.543 us; speedup vs baseline: 3.7902x; 1.6032x over previous
//
#include <hip/hip_runtime.h>
#include <cmath>

namespace {
constexpr int Bz  = 8;
constexpr int L0c = 384;
constexpr int Lc  = 385;
constexpr int Dc  = 128;
constexpr int Hc  = 8;
constexpr int KHc = 16;           // 2 distance groups * 8 heads
constexpr int NITER = 4;
constexpr int BLDc = Bz * Lc * Dc;   // 394240
constexpr int QHS = 388;             // qh fp32 row stride
constexpr int LpadT = 400;           // transposed-plane row stride (ushort)
constexpr float NEGV = 1e9f;

// ---- float workspace offsets
constexpr size_t OFF_UNARY = 0;
constexpr size_t OFF_QZ    = OFF_UNARY + BLDc;
constexpr size_t OFF_MPAD  = OFF_QZ + BLDc;                       // 3584
constexpr size_t OFF_QH    = OFF_MPAD + 3584;                     // 64*385*388
constexpr size_t OFF_GP2   = OFF_QH + (size_t)Bz * Hc * Lc * QHS; // 16*BLDc
constexpr size_t OFF_HP2   = OFF_GP2 + (size_t)16 * BLDc;         // 16*BLDc
constexpr size_t FLOAT_END = OFF_HP2 + (size_t)16 * BLDc;

// ---- ushort offsets from us = (ushort*)(ws + FLOAT_END)
constexpr size_t SZQ    = (size_t)Bz * KHc * Lc * Dc;             // 6307840
constexpr size_t SZQT   = (size_t)Bz * KHc * Dc * LpadT;          // 6553600
constexpr size_t SZT    = (size_t)2 * Hc * Dc * Dc;               // 262144
constexpr size_t U_QZH  = 0;
constexpr size_t U_QZL  = U_QZH + BLDc + 8192;
constexpr size_t U_TABH = U_QZL + BLDc + 8192;
constexpr size_t U_TABL = U_TABH + SZT + 64;
constexpr size_t U_TBAH = U_TABL + SZT + 64;
constexpr size_t U_TBAL = U_TBAH + SZT + 64;
constexpr size_t U_QIH  = U_TBAL + SZT + 64;
constexpr size_t U_QIL  = U_QIH + SZQ + 8192;
constexpr size_t U_QITH = U_QIL + SZQ + 8192;
constexpr size_t U_QITL = U_QITH + SZQT + 64;
constexpr size_t U_QJTH = U_QITL + SZQT + 64;
constexpr size_t U_QJTL = U_QJTH + SZQT + 64;
// total ws ~= 173 MB
} // namespace

typedef __attribute__((ext_vector_type(8))) short bh8_t;
typedef __attribute__((ext_vector_type(4))) float f4_t;
#define MFMA16(a, b, c) __builtin_amdgcn_mfma_f32_16x16x32_bf16((a), (b), (c), 0, 0, 0)

__device__ inline ushort f2bf(float x) {
  uint u = __float_as_uint(x);
  uint r = (u + 0x7FFFu + ((u >> 16) & 1u)) >> 16;
  return (ushort)r;
}
__device__ inline float bf2f(ushort h) { return __uint_as_float(((uint)h) << 16); }
// swizzled ushort offset of 16B group (row, g): bijective, conflict-free b128 access
__device__ inline int slot8(int row, int g) { return (((row << 2) | (g ^ (row & 3))) << 3); }

union U8 { ushort u[8]; uint4 v; };

// ---------------------------------------------------------------- init
__global__ __launch_bounds__(256) void k_init(
    const float* __restrict__ x, const float* __restrict__ mask,
    float* __restrict__ unary, float* __restrict__ qz, float* __restrict__ mpad) {
  int idx = blockIdx.x * 256 + threadIdx.x;
  if (idx >= BLDc) return;
  int d  = idx & (Dc - 1);
  int zi = idx >> 7;
  int i  = zi % Lc;
  int z  = zi / Lc;
  float u = 0.f, m = 1.f;
  if (i > 0) {
    u = x[((size_t)z * L0c + (i - 1)) * Dc + d];
    m = (mask[(size_t)z * L0c + (i - 1)] != 0.f) ? 1.f : 0.f;
  }
  unary[idx] = u;
  qz[idx]    = u * m;
  if (d == 0) mpad[zi] = m;
}

// T[k,a,b,c] -> hi/lo packs: Tab*[kc][a][b], Tba*[kc][b][a]
__global__ __launch_bounds__(256) void k_packT(
    const float* __restrict__ T, ushort* __restrict__ TabH, ushort* __restrict__ TabL,
    ushort* __restrict__ TbaH, ushort* __restrict__ TbaL) {
  int idx = blockIdx.x * 256 + threadIdx.x;
  if (idx >= 2 * Dc * Dc * Hc) return;
  int c = idx & 7;
  int t = idx >> 3;
  int b = t & 127; t >>= 7;
  int a = t & 127; t >>= 7;
  int k = t;
  float v = T[idx];
  ushort h = f2bf(v);
  ushort l = f2bf(v - bf2f(h));
  int kc = k * Hc + c;
  size_t oab = (size_t)kc * Dc * Dc + (size_t)a * Dc + b;
  size_t oba = (size_t)kc * Dc * Dc + (size_t)b * Dc + a;
  TabH[oab] = h; TabL[oab] = l;
  TbaH[oba] = h; TbaL[oba] = l;
}

// ---------------------------------------------------------------- softmax over d + hi/lo emit
__global__ __launch_bounds__(128) void k_softmax_z(
    const float* __restrict__ qz, const float* __restrict__ mpad,
    ushort* __restrict__ qhi, ushort* __restrict__ qlo) {
  int row = blockIdx.x;     // z*L + i
  int t = threadIdx.x;
  float v = qz[(size_t)row * Dc + t];
  float m = v;
  #pragma unroll
  for (int o = 32; o > 0; o >>= 1) m = fmaxf(m, __shfl_xor(m, o));
  __shared__ float red[2];
  if ((t & 63) == 0) red[t >> 6] = m;
  __syncthreads();
  m = fmaxf(red[0], red[1]);
  __syncthreads();
  float e = __expf(v - m);
  float s = e;
  #pragma unroll
  for (int o = 32; o > 0; o >>= 1) s += __shfl_xor(s, o);
  if ((t & 63) == 0) red[t >> 6] = s;
  __syncthreads();
  s = red[0] + red[1];
  float r = e / s * mpad[row];
  size_t o = (size_t)row * Dc + t;
  ushort h = f2bf(r);
  qhi[o] = h;
  qlo[o] = f2bf(r - bf2f(h));
}

// ---------------------------------------------------------------- Qi/Qj (MFMA split-bf16)
// which=0: Qi[i][b] = sum_a qzs[i,a]*Tab[a][b]   (B-source: Tba[b][a], k=a contiguous)
// which=1: Qj[j][a] = sum_b qzs[j,b]*Tab[a][b]   (B-source: Tab[a][b], k=b contiguous)
__global__ __launch_bounds__(256) void k_qiqj(
    const ushort* __restrict__ qzH, const ushort* __restrict__ qzL,
    const ushort* __restrict__ TabH, const ushort* __restrict__ TabL,
    const ushort* __restrict__ TbaH, const ushort* __restrict__ TbaL,
    ushort* __restrict__ QiH, ushort* __restrict__ QiL,
    ushort* __restrict__ QiTH, ushort* __restrict__ QiTL,
    ushort* __restrict__ QjTH, ushort* __restrict__ QjTL) {
  __shared__ __align__(16) char pool[24576];
  ushort* Ath = (ushort*)pool;            // 64x32
  ushort* Atl = (ushort*)(pool + 4096);
  ushort* Bth = (ushort*)(pool + 8192);   // 128x32
  ushort* Btl = (ushort*)(pool + 16384);
  const int it = blockIdx.x, z = blockIdx.y;
  const int kc = blockIdx.z >> 1, which = blockIdx.z & 1;
  const int i0 = it * 64;
  const int tid = threadIdx.x;
  const int wid = tid >> 6, ln = tid & 63;
  const int wr = wid >> 1, wc = wid & 1;
  const int lr = ln & 15, lg = ln >> 4;
  const ushort* Ah = qzH + (size_t)z * Lc * Dc;
  const ushort* Al = qzL + (size_t)z * Lc * Dc;
  const ushort* Bh = (which ? TabH : TbaH) + (size_t)kc * Dc * Dc;
  const ushort* Bl = (which ? TabL : TbaL) + (size_t)kc * Dc * Dc;
  f4_t acc[2][4] = {};
  const uint4 zq4 = make_uint4(0u, 0u, 0u, 0u);
  const int srow = tid >> 2, sg = tid & 3;
  const bool aok = (i0 + srow) < Lc;
  for (int k0 = 0; k0 < Dc; k0 += 32) {
    __syncthreads();
    size_t ao = (size_t)(i0 + srow) * Dc + k0 + sg * 8;
    *reinterpret_cast<uint4*>(&Ath[slot8(srow, sg)]) = aok ? *reinterpret_cast<const uint4*>(Ah + ao) : zq4;
    *reinterpret_cast<uint4*>(&Atl[slot8(srow, sg)]) = aok ? *reinterpret_cast<const uint4*>(Al + ao) : zq4;
    #pragma unroll
    for (int rep = 0; rep < 2; rep++) {
      int e = tid + rep * 256;
      int col = e >> 2, g = e & 3;
      size_t bo = (size_t)col * Dc + k0 + g * 8;
      *reinterpret_cast<uint4*>(&Bth[slot8(col, g)]) = *reinterpret_cast<const uint4*>(Bh + bo);
      *reinterpret_cast<uint4*>(&Btl[slot8(col, g)]) = *reinterpret_cast<const uint4*>(Bl + bo);
    }
    __syncthreads();
    bh8_t ah[2], al2[2];
    #pragma unroll
    for (int fi = 0; fi < 2; fi++) {
      int ra = wr * 32 + fi * 16 + lr;
      ah[fi]  = *reinterpret_cast<const bh8_t*>(&Ath[slot8(ra, lg)]);
      al2[fi] = *reinterpret_cast<const bh8_t*>(&Atl[slot8(ra, lg)]);
    }
    #pragma unroll
    for (int fj = 0; fj < 4; fj++) {
      int rb = wc * 64 + fj * 16 + lr;
      bh8_t bh = *reinterpret_cast<const bh8_t*>(&Bth[slot8(rb, lg)]);
      bh8_t bl = *reinterpret_cast<const bh8_t*>(&Btl[slot8(rb, lg)]);
      #pragma unroll
      for (int fi = 0; fi < 2; fi++) {
        acc[fi][fj] = MFMA16(ah[fi], bh, acc[fi][fj]);
        acc[fi][fj] = MFMA16(ah[fi], bl, acc[fi][fj]);
        acc[fi][fj] = MFMA16(al2[fi], bh, acc[fi][fj]);
      }
    }
  }
  // hi/lo in registers
  ushort hreg[2][4][4], lreg[2][4][4];
  #pragma unroll
  for (int fi = 0; fi < 2; fi++)
    #pragma unroll
    for (int fj = 0; fj < 4; fj++)
      #pragma unroll
      for (int r = 0; r < 4; r++) {
        float v = acc[fi][fj][r];
        ushort h = f2bf(v);
        hreg[fi][fj][r] = h;
        lreg[fi][fj][r] = f2bf(v - bf2f(h));
      }
  ushort* Tr = (ushort*)pool;   // [64][132] row-major, 16896 B
  const size_t plane = (size_t)(z * KHc + kc);
  ushort* OutT = (which ? QjTH : QiTH);   // per-pass offset below
  ushort* OutTl = (which ? QjTL : QiTL);
  #pragma unroll
  for (int pass = 0; pass < 2; pass++) {
    __syncthreads();
    #pragma unroll
    for (int fi = 0; fi < 2; fi++)
      #pragma unroll
      for (int fj = 0; fj < 4; fj++) {
        int col = wc * 64 + fj * 16 + lr;
        #pragma unroll
        for (int r = 0; r < 4; r++) {
          int row = wr * 32 + fi * 16 + lg * 4 + r;
          Tr[row * 132 + col] = pass ? lreg[fi][fj][r] : hreg[fi][fj][r];
        }
      }
    __syncthreads();
    if (which == 0) {   // row-major Qi for F
      ushort* Out = (pass ? QiL : QiH) + plane * Lc * Dc;
      for (int e = tid; e < 1024; e += 256) {
        int row = e >> 4, cg = e & 15;
        int i = i0 + row;
        if (i < Lc) {
          ushort4 w0 = *reinterpret_cast<const ushort4*>(&Tr[row * 132 + cg * 8]);
          ushort4 w1 = *reinterpret_cast<const ushort4*>(&Tr[row * 132 + cg * 8 + 4]);
          *reinterpret_cast<ushort4*>(Out + (size_t)i * Dc + cg * 8) = w0;
          *reinterpret_cast<ushort4*>(Out + (size_t)i * Dc + cg * 8 + 4) = w1;
        }
      }
    }
    ushort* OT = (pass ? OutTl : OutT) + plane * Dc * LpadT;
    for (int e = tid; e < 1024; e += 256) {
      int brow = e >> 3, g = e & 7;
      int ii = i0 + g * 8;
      if (ii < LpadT) {
        U8 tmp;
        #pragma unroll
        for (int q = 0; q < 8; q++) tmp.u[q] = Tr[(g * 8 + q) * 132 + brow];
        *reinterpret_cast<uint4*>(OT + (size_t)brow * LpadT + ii) = tmp.v;
      }
    }
  }
}

// ---------------------------------------------------------------- F -> qh logits (MFMA, split-bf16)
// 1-D swizzled grid: 3136 blocks; XCD = c; 7 tj-sharers adjacent per XCD.
__global__ __launch_bounds__(256) void k_F(
    const ushort* __restrict__ QiH, const ushort* __restrict__ QiL,
    const ushort* __restrict__ qzH, const ushort* __restrict__ qzL,
    const float* __restrict__ mpad, float* __restrict__ qh) {
  __shared__ ushort A0h[2048], A0l[2048], A1h[2048], A1l[2048], Bh[2048], Bl[2048];
  const int id = blockIdx.x;
  const int q8 = id & 7;
  const int t = id >> 3;                 // 0..391
  const int gl = t / 7, tj = t - gl * 7; // gl 0..55
  const int g = q8 + (gl << 3);          // 0..447
  const int ti = g >> 6;                 // 0..6
  const int rem = g & 63;
  const int z = rem >> 3, c = rem & 7;
  const int i0 = ti * 64, j0 = tj * 64;
  const bool mixed = (ti == tj);
  const int tid = threadIdx.x;
  const int wid = tid >> 6, ln = tid & 63;
  const int wr = wid >> 1, wc = wid & 1;
  const int lr = ln & 15, lg = ln >> 4;
  const ushort* p0h = QiH + (size_t)(z * KHc + c) * Lc * Dc;
  const ushort* p0l = QiL + (size_t)(z * KHc + c) * Lc * Dc;
  const ushort* p1h = QiH + (size_t)(z * KHc + Hc + c) * Lc * Dc;
  const ushort* p1l = QiL + (size_t)(z * KHc + Hc + c) * Lc * Dc;
  const ushort* bhp = qzH + (size_t)z * Lc * Dc;
  const ushort* blp = qzL + (size_t)z * Lc * Dc;
  const ushort* sAh = (!mixed && tj < ti) ? p1h : p0h;
  const ushort* sAl = (!mixed && tj < ti) ? p1l : p0l;
  f4_t acc0[2][2] = {};
  f4_t acc1[2][2] = {};
  const int srow = tid >> 2, sg = tid & 3;
  const int so = slot8(srow, sg);
  const bool aok = (i0 + srow) < Lc;
  const bool bok = (j0 + srow) < Lc;
  const size_t aoff = (size_t)(i0 + srow) * Dc + sg * 8;
  const size_t boff = (size_t)(j0 + srow) * Dc + sg * 8;
  const uint4 zq = make_uint4(0u, 0u, 0u, 0u);
  for (int k0 = 0; k0 < Dc; k0 += 32) {
    __syncthreads();
    *reinterpret_cast<uint4*>(&A0h[so]) = aok ? *reinterpret_cast<const uint4*>(sAh + aoff + k0) : zq;
    *reinterpret_cast<uint4*>(&A0l[so]) = aok ? *reinterpret_cast<const uint4*>(sAl + aoff + k0) : zq;
    *reinterpret_cast<uint4*>(&Bh[so])  = bok ? *reinterpret_cast<const uint4*>(bhp + boff + k0) : zq;
    *reinterpret_cast<uint4*>(&Bl[so])  = bok ? *reinterpret_cast<const uint4*>(blp + boff + k0) : zq;
    if (mixed) {
      *reinterpret_cast<uint4*>(&A1h[so]) = aok ? *reinterpret_cast<const uint4*>(p1h + aoff + k0) : zq;
      *reinterpret_cast<uint4*>(&A1l[so]) = aok ? *reinterpret_cast<const uint4*>(p1l + aoff + k0) : zq;
    }
    __syncthreads();
    bh8_t ah[2], al[2], bhv[2], blv[2];
    #pragma unroll
    for (int f = 0; f < 2; f++) {
      int ra = wr * 32 + f * 16 + lr;
      ah[f] = *reinterpret_cast<const bh8_t*>(&A0h[slot8(ra, lg)]);
      al[f] = *reinterpret_cast<const bh8_t*>(&A0l[slot8(ra, lg)]);
      int rb = wc * 32 + f * 16 + lr;
      bhv[f] = *reinterpret_cast<const bh8_t*>(&Bh[slot8(rb, lg)]);
      blv[f] = *reinterpret_cast<const bh8_t*>(&Bl[slot8(rb, lg)]);
    }
    #pragma unroll
    for (int fi = 0; fi < 2; fi++)
      #pragma unroll
      for (int fj = 0; fj < 2; fj++) {
        acc0[fi][fj] = MFMA16(ah[fi], bhv[fj], acc0[fi][fj]);
        acc0[fi][fj] = MFMA16(ah[fi], blv[fj], acc0[fi][fj]);
        acc0[fi][fj] = MFMA16(al[fi], bhv[fj], acc0[fi][fj]);
      }
    if (mixed) {
      bh8_t a1h[2], a1l[2];
      #pragma unroll
      for (int f = 0; f < 2; f++) {
        int ra = wr * 32 + f * 16 + lr;
        a1h[f] = *reinterpret_cast<const bh8_t*>(&A1h[slot8(ra, lg)]);
        a1l[f] = *reinterpret_cast<const bh8_t*>(&A1l[slot8(ra, lg)]);
      }
      #pragma unroll
      for (int fi = 0; fi < 2; fi++)
        #pragma unroll
        for (int fj = 0; fj < 2; fj++) {
          acc1[fi][fj] = MFMA16(a1h[fi], bhv[fj], acc1[fi][fj]);
          acc1[fi][fj] = MFMA16(a1h[fi], blv[fj], acc1[fi][fj]);
          acc1[fi][fj] = MFMA16(a1l[fi], bhv[fj], acc1[fi][fj]);
        }
    }
  }
  float* qrow = qh + (size_t)(z * Hc + c) * Lc * QHS;
  #pragma unroll
  for (int fi = 0; fi < 2; fi++)
    #pragma unroll
    for (int fj = 0; fj < 2; fj++)
      #pragma unroll
      for (int r = 0; r < 4; r++) {
        int i = i0 + wr * 32 + fi * 16 + lg * 4 + r;
        int j = j0 + wc * 32 + fj * 16 + lr;
        if (i >= Lc || j >= Lc) continue;
        float mi = mpad[z * Lc + i], mj = mpad[z * Lc + j];
        float val;
        if (i == j || mi == 0.f || mj == 0.f) val = -NEGV;
        else {
          float sacc = (mixed && i > j) ? acc1[fi][fj][r] : acc0[fi][fj][r];
          val = sacc * 128.f;
        }
        qrow[(size_t)i * QHS + j] = val;
      }
}

// ---------------------------------------------------------------- softmax over j; zero root row
__global__ __launch_bounds__(128) void k_softmax_h(float* __restrict__ qh) {
  const int row = blockIdx.x;      // (z*H + c)*L + i
  const int i = row % Lc;
  const int t = threadIdx.x;
  float* p = qh + (size_t)row * QHS;
  if (i == 0) {
    for (int j = t; j < Lc; j += 128) p[j] = 0.f;
    return;
  }
  float v[4];
  float m = -INFINITY;
  #pragma unroll
  for (int q = 0; q < 4; q++) {
    int j = t + q * 128;
    v[q] = (j < Lc) ? p[j] : -INFINITY;
    m = fmaxf(m, v[q]);
  }
  #pragma unroll
  for (int o = 32; o > 0; o >>= 1) m = fmaxf(m, __shfl_xor(m, o));
  __shared__ float red[2];
  if ((t & 63) == 0) red[t >> 6] = m;
  __syncthreads();
  m = fmaxf(red[0], red[1]);
  __syncthreads();
  float s = 0.f;
  #pragma unroll
  for (int q = 0; q < 4; q++) {
    int j = t + q * 128;
    v[q] = (j < Lc) ? __expf(v[q] - m) : 0.f;
    s += v[q];
  }
  #pragma unroll
  for (int o = 32; o > 0; o >>= 1) s += __shfl_xor(s, o);
  if ((t & 63) == 0) red[t >> 6] = s;
  __syncthreads();
  s = red[0] + red[1];
  float inv = 1.f / s;
  #pragma unroll
  for (int q = 0; q < 4; q++) {
    int j = t + q * 128;
    if (j < Lc) p[j] = v[q] * inv;
  }
}

// ---------------------------------------------------------------- fused G/Hm (MFMA split-bf16, split-K, XCD-swizzled)
// 1-D grid 1792: XCD = z; 7 row-tiles sharing a B-plane adjacent per XCD.
__global__ __launch_bounds__(256) void k_GH2(
    const float* __restrict__ qh,
    const ushort* __restrict__ QiTH, const ushort* __restrict__ QiTL,
    const ushort* __restrict__ QjTH, const ushort* __restrict__ QjTL,
    float* __restrict__ Gp2, float* __restrict__ Hp2) {
  __shared__ ushort Ath[2048], Atl[2048];
  __shared__ ushort Bth[4096], Btl[4096];
  const int id = blockIdx.x;
  const int q8 = id & 7;
  const int t = id >> 3;                 // 0..223
  const int gl = t / 7, xt = t - gl * 7; // gl 0..31
  const int g = q8 + (gl << 3);          // 0..255
  const int z = g & 7;
  const int r = g >> 3;                  // 0..31
  const int c = r & 7, sp = (r >> 3) & 1, which = r >> 4;
  const int r0 = xt * 64;
  const int tid = threadIdx.x;
  const int wid = tid >> 6, ln = tid & 63;
  const int wr = wid >> 1, wc = wid & 1;
  const int lr = ln & 15, lg = ln >> 4;
  const int rowmax = min(r0 + 63, Lc - 1);
  const int klo = sp ? 192 : 0, khi = sp ? Lc : 192;
  const float* qhp = qh + (size_t)(z * Hc + c) * Lc * QHS;
  const ushort* BH = which ? QiTH : QjTH;
  const ushort* BL = which ? QiTL : QjTL;
  f4_t acc[2][4] = {};

  for (int kc = klo; kc < khi; kc += 32) {
    const int kmax = min(kc + 31, Lc - 1);
    for (int p = 0; p < 2; p++) {
      const bool rl = (p == 0) != (which == 1);   // keep R<kg if rl else R>kg
      const bool has = rl ? (r0 < kmax) : (rowmax > kc);
      if (!has) continue;
      __syncthreads();
      // ---- stage A (64 rows x 32 k), masked hi/lo
      if (which == 0) {
        int srow = tid >> 2, sg = tid & 3;
        int R = r0 + srow;
        float4 v0 = make_float4(0.f,0.f,0.f,0.f), v1 = v0;
        if (R < Lc) {
          v0 = *reinterpret_cast<const float4*>(qhp + (size_t)R * QHS + kc + sg * 8);
          v1 = *reinterpret_cast<const float4*>(qhp + (size_t)R * QHS + kc + sg * 8 + 4);
        }
        float vv[8] = {v0.x, v0.y, v0.z, v0.w, v1.x, v1.y, v1.z, v1.w};
        U8 hh, ll;
        #pragma unroll
        for (int q = 0; q < 8; q++) {
          int kg = kc + sg * 8 + q;
          bool keep = (R < Lc) && (kg < Lc) && (rl ? (R < kg) : (R > kg));
          float x = keep ? vv[q] : 0.f;
          hh.u[q] = f2bf(x);
          ll.u[q] = f2bf(x - bf2f(hh.u[q]));
        }
        int off = slot8(srow, sg);
        *reinterpret_cast<uint4*>(&Ath[off]) = hh.v;
        *reinterpret_cast<uint4*>(&Atl[off]) = ll.v;
      } else {
        // A[row=j][k=i]: transpose 32x64 block of qh
        int rr = tid >> 3, cg = tid & 7;
        int I = kc + rr;
        float4 v0 = make_float4(0.f,0.f,0.f,0.f), v1 = v0;
        if (I < Lc) {
          v0 = *reinterpret_cast<const float4*>(qhp + (size_t)I * QHS + r0 + cg * 8);
          v1 = *reinterpret_cast<const float4*>(qhp + (size_t)I * QHS + r0 + cg * 8 + 4);
        }
        float vv[8] = {v0.x, v0.y, v0.z, v0.w, v1.x, v1.y, v1.z, v1.w};
        #pragma unroll
        for (int q = 0; q < 8; q++) {
          int jl = cg * 8 + q;
          int R = r0 + jl;
          bool keep = (I < Lc) && (R < Lc) && (rl ? (R < I) : (R > I));
          float x = keep ? vv[q] : 0.f;
          ushort hh = f2bf(x);
          int off = slot8(jl, rr >> 3) + (rr & 7);
          Ath[off] = hh;
          Atl[off] = f2bf(x - bf2f(hh));
        }
      }
      // ---- stage B (128 rows x 32 k) from transposed planes: pure uint4
      {
        const size_t pb = (size_t)(z * KHc + p * Hc + c) * Dc * LpadT + kc;
        #pragma unroll
        for (int rep = 0; rep < 2; rep++) {
          int e = tid + rep * 256;
          int brow = e >> 2, gg = e & 3;
          size_t go = pb + (size_t)brow * LpadT + gg * 8;
          int off = slot8(brow, gg);
          *reinterpret_cast<uint4*>(&Bth[off]) = *reinterpret_cast<const uint4*>(BH + go);
          *reinterpret_cast<uint4*>(&Btl[off]) = *reinterpret_cast<const uint4*>(BL + go);
        }
      }
      __syncthreads();
      // ---- fragments + MFMA (3-term split)
      bh8_t ah[2], al[2];
      #pragma unroll
      for (int fi = 0; fi < 2; fi++) {
        int ra = wr * 32 + fi * 16 + lr;
        ah[fi] = *reinterpret_cast<const bh8_t*>(&Ath[slot8(ra, lg)]);
        al[fi] = *reinterpret_cast<const bh8_t*>(&Atl[slot8(ra, lg)]);
      }
      #pragma unroll
      for (int fj = 0; fj < 4; fj++) {
        int rb = wc * 64 + fj * 16 + lr;
        bh8_t bh = *reinterpret_cast<const bh8_t*>(&Bth[slot8(rb, lg)]);
        bh8_t bl = *reinterpret_cast<const bh8_t*>(&Btl[slot8(rb, lg)]);
        #pragma unroll
        for (int fi = 0; fi < 2; fi++) {
          acc[fi][fj] = MFMA16(ah[fi], bh, acc[fi][fj]);
          acc[fi][fj] = MFMA16(ah[fi], bl, acc[fi][fj]);
          acc[fi][fj] = MFMA16(al[fi], bh, acc[fi][fj]);
        }
      }
    }
  }
  float* outp = (which ? Hp2 : Gp2) + ((size_t)(sp * Hc + c) * Bz + z) * (size_t)Lc * Dc;
  #pragma unroll
  for (int fi = 0; fi < 2; fi++)
    #pragma unroll
    for (int r4 = 0; r4 < 4; r4++) {
      int row = r0 + wr * 32 + fi * 16 + lg * 4 + r4;
      if (row >= Lc) continue;
      #pragma unroll
      for (int fj = 0; fj < 4; fj++) {
        int col = wc * 64 + fj * 16 + lr;
        outp[(size_t)row * Dc + col] = acc[fi][fj][r4];
      }
    }
}

// ---------------------------------------------------------------- combine: qz = (unary + G + Hm)*m1
__global__ __launch_bounds__(256) void k_combine(
    const float* __restrict__ unary, const float* __restrict__ Gp2,
    const float* __restrict__ Hp2, const float* __restrict__ mpad,
    float* __restrict__ qz, float* __restrict__ out, int last) {
  int idx = blockIdx.x * 256 + threadIdx.x;
  if (idx >= BLDc) return;
  int d  = idx & (Dc - 1);
  int zi = idx >> 7;
  int i  = zi % Lc;
  int z  = zi / Lc;
  float s = unary[idx];
  #pragma unroll
  for (int q = 0; q < 16; q++) s += Gp2[(size_t)q * BLDc + idx] + Hp2[(size_t)q * BLDc + idx];
  s *= mpad[zi];
  if (last) {
    if (i > 0) out[((size_t)z * L0c + (i - 1)) * Dc + d] = s;
  } else {
    qz[idx] = s;
  }
}

// ---------------------------------------------------------------- launch
extern "C" void kernel_launch(void* const* d_in, const int* in_sizes, int n_in,
                              void* d_out, int out_size, void* d_ws, size_t ws_size,
                              hipStream_t stream) {
  const float* x    = (const float*)d_in[0];
  const float* mask = (const float*)d_in[1];
  const float* tern = (const float*)d_in[2];
  float* ws = (float*)d_ws;

  float* unary = ws + OFF_UNARY;
  float* qz    = ws + OFF_QZ;
  float* mpad  = ws + OFF_MPAD;
  float* qh    = ws + OFF_QH;
  float* gp2   = ws + OFF_GP2;
  float* hp2   = ws + OFF_HP2;
  ushort* us   = (ushort*)(ws + FLOAT_END);
  ushort* qzH  = us + U_QZH;
  ushort* qzL  = us + U_QZL;
  ushort* tabH = us + U_TABH;
  ushort* tabL = us + U_TABL;
  ushort* tbaH = us + U_TBAH;
  ushort* tbaL = us + U_TBAL;
  ushort* qiH  = us + U_QIH;
  ushort* qiL  = us + U_QIL;
  ushort* qiTH = us + U_QITH;
  ushort* qiTL = us + U_QITL;
  ushort* qjTH = us + U_QJTH;
  ushort* qjTL = us + U_QJTL;

  k_init<<<(BLDc + 255) / 256, 256, 0, stream>>>(x, mask, unary, qz, mpad);
  k_packT<<<(2 * Dc * Dc * Hc) / 256, 256, 0, stream>>>(tern, tabH, tabL, tbaH, tbaL);

  for (int it = 0; it < NITER; it++) {
    k_softmax_z<<<Bz * Lc, 128, 0, stream>>>(qz, mpad, qzH, qzL);
    k_qiqj<<<dim3(7, Bz, 32), 256, 0, stream>>>(qzH, qzL, tabH, tabL, tbaH, tbaL,
                                                qiH, qiL, qiTH, qiTL, qjTH, qjTL);
    k_F<<<3136, 256, 0, stream>>>(qiH, qiL, qzH, qzL, mpad, qh);
    k_softmax_h<<<Bz * Hc * Lc, 128, 0, stream>>>(qh);
    k_GH2<<<1792, 256, 0, stream>>>(qh, qiTH, qiTL, qjTH, qjTL, gp2, hp2);
    k_combine<<<(BLDc + 255) / 256, 256, 0, stream>>>(
        unary, gp2, hp2, mpad, qz, (float*)d_out, (it == NITER - 1) ? 1 : 0);
  }
}